// Round 1
// baseline (863.409 us; speedup 1.0000x reference)
//
#include <hip/hip_runtime.h>

// Problem constants
#define BGR   256      // graphs
#define NPG   128      // nodes per graph
#define EPG   512      // edges per graph
#define DIN   128
#define DD    256
#define DD2   512
#define NTOT  (BGR * NPG)   // 32768
#define ETOT  (BGR * EPG)   // 131072
#define NRES  (EPG / 2)     // 256
#define BN_CHUNKS 128
#define BN_ROWS_PER_CHUNK 256   // 128*256 = 32768

// Output layout (floats)
#define OFF_CEI  0
#define OFF_CW   (2 * BGR * NRES)              // 131072
#define OFF_FEI  (OFF_CW + BGR * NRES)         // 196608
#define OFF_FW   (OFF_FEI + 2 * BGR * NRES)    // 327680
#define OFF_PRED (OFF_FW + BGR * NRES)         // 393216

// ---------------------------------------------------------------------------
// CSR build: one block per graph, 128 threads (one per local node).
// Stable in edge order (matches sequential segment_sum semantics).
__global__ __launch_bounds__(NPG) void build_csr(const int* __restrict__ ei,
                                                 int* __restrict__ csr_edges,
                                                 int* __restrict__ csr_start) {
    const int b = blockIdx.x;
    __shared__ int dstl[EPG];
    __shared__ int cnts[NPG];
    const int* col = ei + ETOT + b * EPG;
    for (int i = threadIdx.x; i < EPG; i += NPG) dstl[i] = col[i] - b * NPG;
    __syncthreads();
    const int node = threadIdx.x;
    int cnt = 0;
    for (int e = 0; e < EPG; ++e) cnt += (dstl[e] == node);
    cnts[node] = cnt;
    __syncthreads();
    int start = 0;
    for (int k = 0; k < node; ++k) start += cnts[k];
    csr_start[b * NPG + node] = b * EPG + start;
    if (b == 0 && node == 0) csr_start[NTOT] = ETOT;
    int kk = b * EPG + start;
    for (int e = 0; e < EPG; ++e)
        if (dstl[e] == node) csr_edges[kk++] = b * EPG + e;
}

// ---------------------------------------------------------------------------
// s = h + segment_sum(h[row]) ; one block per node, blockDim.x == ncols
__global__ void aggregate_add(const float* __restrict__ h,
                              const int* __restrict__ rowidx,
                              const int* __restrict__ csr_edges,
                              const int* __restrict__ csr_start,
                              float* __restrict__ outp) {
    const int i = blockIdx.x;
    const int ncols = blockDim.x;
    const int t = threadIdx.x;
    float acc = h[(size_t)i * ncols + t];
    const int s = csr_start[i], e2 = csr_start[i + 1];
    for (int p = s; p < e2; ++p) {
        const int r = rowidx[csr_edges[p]];
        acc += h[(size_t)r * ncols + t];
    }
    outp[(size_t)i * ncols + t] = acc;
}

// ---------------------------------------------------------------------------
// fp32 GEMM: C[M,Nn] = A[M,K] @ B[K,Nn] + bias.  64x64 tile, BK=16, 256 thr,
// 4x4 micro-tile per thread. M%64==0, Nn%64==0, K%16==0 guaranteed.
__global__ __launch_bounds__(256) void gemm_bias(const float* __restrict__ A,
                                                 const float* __restrict__ Bw,
                                                 const float* __restrict__ bias,
                                                 float* __restrict__ C,
                                                 int M, int Nn, int K) {
    __shared__ float As[16][64];
    __shared__ float Bs[16][64];
    const int tid = threadIdx.x;
    const int tx = tid & 15;     // n direction
    const int ty = tid >> 4;     // m direction
    const int mBase = blockIdx.y * 64;
    const int nBase = blockIdx.x * 64;
    const int mrow  = tid >> 2;            // 0..63
    const int kcolA = (tid & 3) << 2;      // 0,4,8,12
    const int krowB = tid >> 4;            // 0..15
    const int ncolB = (tid & 15) << 2;     // 0..60
    float acc[4][4] = {};
    for (int k0 = 0; k0 < K; k0 += 16) {
        const float4 a4 = *(const float4*)(A + (size_t)(mBase + mrow) * K + (k0 + kcolA));
        const float4 b4 = *(const float4*)(Bw + (size_t)(k0 + krowB) * Nn + (nBase + ncolB));
        As[kcolA + 0][mrow] = a4.x;
        As[kcolA + 1][mrow] = a4.y;
        As[kcolA + 2][mrow] = a4.z;
        As[kcolA + 3][mrow] = a4.w;
        *(float4*)&Bs[krowB][ncolB] = b4;
        __syncthreads();
#pragma unroll
        for (int k = 0; k < 16; ++k) {
            float ar[4], br[4];
#pragma unroll
            for (int i = 0; i < 4; ++i) ar[i] = As[k][ty * 4 + i];
#pragma unroll
            for (int j = 0; j < 4; ++j) br[j] = Bs[k][tx * 4 + j];
#pragma unroll
            for (int i = 0; i < 4; ++i)
#pragma unroll
                for (int j = 0; j < 4; ++j)
                    acc[i][j] = fmaf(ar[i], br[j], acc[i][j]);
        }
        __syncthreads();
    }
#pragma unroll
    for (int i = 0; i < 4; ++i) {
        const int m = mBase + ty * 4 + i;
        const int n0 = nBase + tx * 4;
        float4 o;
        o.x = acc[i][0] + bias[n0 + 0];
        o.y = acc[i][1] + bias[n0 + 1];
        o.z = acc[i][2] + bias[n0 + 2];
        o.w = acc[i][3] + bias[n0 + 3];
        *(float4*)&C[(size_t)m * Nn + n0] = o;
    }
}

// ---------------------------------------------------------------------------
// BN statistics: per-column partial double sums, fixed order (deterministic).
__global__ __launch_bounds__(256) void bn_stats(const float* __restrict__ z, int ncols,
                                                double* __restrict__ psum,
                                                double* __restrict__ psumsq) {
    const int c = blockIdx.x * 256 + threadIdx.x;
    const int r0 = blockIdx.y * BN_ROWS_PER_CHUNK;
    double s = 0.0, s2 = 0.0;
    const float* p = z + (size_t)r0 * ncols + c;
    for (int r = 0; r < BN_ROWS_PER_CHUNK; ++r) {
        const double v = (double)p[(size_t)r * ncols];
        s += v;
        s2 += v * v;
    }
    psum[(size_t)blockIdx.y * ncols + c] = s;
    psumsq[(size_t)blockIdx.y * ncols + c] = s2;
}

__global__ __launch_bounds__(256) void bn_finalize(const double* __restrict__ psum,
                                                   const double* __restrict__ psumsq,
                                                   const float* __restrict__ g,
                                                   const float* __restrict__ be,
                                                   int ncols,
                                                   float* __restrict__ scale,
                                                   float* __restrict__ shift) {
    const int c = blockIdx.x * 256 + threadIdx.x;
    double s = 0.0, s2 = 0.0;
    for (int k = 0; k < BN_CHUNKS; ++k) {
        s += psum[(size_t)k * ncols + c];
        s2 += psumsq[(size_t)k * ncols + c];
    }
    const double mean = s / (double)NTOT;
    const double var = s2 / (double)NTOT - mean * mean;
    const double rs = 1.0 / sqrt(var + 1e-5);
    const float sc = (float)((double)g[c] * rs);
    scale[c] = sc;
    shift[c] = (float)((double)be[c] - mean * (double)sc);
}

// out = [relu](z*scale+shift) [+ vadd]
__global__ __launch_bounds__(256) void bn_apply(const float* __restrict__ z,
                                                const float* __restrict__ scale,
                                                const float* __restrict__ shift,
                                                const float* __restrict__ vadd,
                                                float* __restrict__ outp,
                                                int ncolmask, int relu) {
    const size_t idx = (size_t)blockIdx.x * 256 + threadIdx.x;
    const int c = (int)(idx & (size_t)ncolmask);
    float v = fmaf(z[idx], scale[c], shift[c]);
    if (relu) v = fmaxf(v, 0.0f);
    if (vadd) v += vadd[c];
    outp[idx] = v;
}

// ---------------------------------------------------------------------------
// Per-node dots with Wl halves: pa[i]=dot(xn[i],Wl[0:256]), pb[i]=dot(xn[i],Wl[256:512])
__global__ __launch_bounds__(256) void node_dots(const float* __restrict__ xn,
                                                 const float* __restrict__ Wl,
                                                 float* __restrict__ pa,
                                                 float* __restrict__ pb) {
    const int wave = threadIdx.x >> 6;
    const int lane = threadIdx.x & 63;
    const int node = blockIdx.x * 4 + wave;
    const float* xr = xn + (size_t)node * DD;
    float sa = 0.0f, sb = 0.0f;
#pragma unroll
    for (int c0 = 0; c0 < DD; c0 += 64) {
        const int c = c0 + lane;
        const float v = xr[c];
        sa = fmaf(v, Wl[c], sa);
        sb = fmaf(v, Wl[DD + c], sb);
    }
#pragma unroll
    for (int off = 32; off >= 1; off >>= 1) {
        sa += __shfl_down(sa, off);
        sb += __shfl_down(sb, off);
    }
    if (lane == 0) {
        pa[node] = sa;
        pb[node] = sb;
    }
}

__global__ __launch_bounds__(256) void pred_kernel(const float* __restrict__ pa,
                                                   const float* __restrict__ pb,
                                                   const int* __restrict__ ei,
                                                   const float* __restrict__ bl,
                                                   float* __restrict__ pred) {
    const int e = blockIdx.x * 256 + threadIdx.x;
    const int r = ei[e];
    const int c = ei[ETOT + e];
    pred[e] = pa[r] + pb[c] + bl[0];
}

// ---------------------------------------------------------------------------
// Per-graph stable descending sort (rank counting) + output gathers.
__global__ __launch_bounds__(EPG) void sort_write(const float* __restrict__ pred,
                                                  const int* __restrict__ ei,
                                                  float* __restrict__ out) {
    __shared__ float pw[EPG];
    __shared__ int ord[EPG];
    const int b = blockIdx.x;
    const int t = threadIdx.x;
    const float v = pred[b * EPG + t];
    pw[t] = v;
    __syncthreads();
    int rank = 0;
    for (int k = 0; k < EPG; ++k) {
        const float u = pw[k];
        rank += (u > v) || (u == v && k < t);
    }
    ord[rank] = t;
    __syncthreads();
    const int j = ord[t];
    const float wv = pw[j];
    const float e0 = (float)ei[b * EPG + j];
    const float e1 = (float)ei[ETOT + b * EPG + j];
    if (t < NRES) {
        out[OFF_CEI + b * NRES + t] = e0;
        out[OFF_CEI + BGR * NRES + b * NRES + t] = e1;
        out[OFF_CW + b * NRES + t] = wv;
    } else {
        const int p = t - NRES;
        out[OFF_FEI + b * NRES + p] = e0;
        out[OFF_FEI + BGR * NRES + b * NRES + p] = e1;
        out[OFF_FW + b * NRES + p] = -wv;
    }
}

// ---------------------------------------------------------------------------
extern "C" void kernel_launch(void* const* d_in, const int* in_sizes, int n_in,
                              void* d_out, int out_size, void* d_ws, size_t ws_size,
                              hipStream_t stream) {
    (void)in_sizes; (void)n_in; (void)out_size; (void)ws_size;
    const float* x    = (const float*)d_in[0];
    const int*   ei   = (const int*)d_in[1];
    // d_in[2] = batch (unused: vfeat rows are identical)
    const float* vemb = (const float*)d_in[3];
    const float* W1a  = (const float*)d_in[4];
    const float* b1a  = (const float*)d_in[5];
    const float* g1a  = (const float*)d_in[6];
    const float* be1a = (const float*)d_in[7];
    const float* W1b  = (const float*)d_in[8];
    const float* b1b  = (const float*)d_in[9];
    const float* g1   = (const float*)d_in[10];
    const float* be1  = (const float*)d_in[11];
    const float* W2a  = (const float*)d_in[12];
    const float* b2a  = (const float*)d_in[13];
    const float* g2a  = (const float*)d_in[14];
    const float* be2a = (const float*)d_in[15];
    const float* W2b  = (const float*)d_in[16];
    const float* b2b  = (const float*)d_in[17];
    const float* g2   = (const float*)d_in[18];
    const float* be2  = (const float*)d_in[19];
    const float* Wl   = (const float*)d_in[20];
    const float* bl   = (const float*)d_in[21];
    float* out = (float*)d_out;

    // workspace carve-up (~137 MB)
    char* wp = (char*)d_ws;
    auto alloc = [&](size_t bytes) -> char* {
        char* r = wp;
        wp += (bytes + 255) & ~(size_t)255;
        return r;
    };
    float*  bufA     = (float*)alloc((size_t)NTOT * 512 * 4);  // z1/z1n, z2/z2n
    float*  bufB     = (float*)alloc((size_t)NTOT * 256 * 4);  // h1/post
    float*  bufC     = (float*)alloc((size_t)NTOT * 256 * 4);  // s1, s2, h2/xn
    double* psum     = (double*)alloc((size_t)BN_CHUNKS * 512 * 8);
    double* psumsq   = (double*)alloc((size_t)BN_CHUNKS * 512 * 8);
    float*  scale    = (float*)alloc(512 * 4);
    float*  shift    = (float*)alloc(512 * 4);
    float*  pa       = (float*)alloc((size_t)NTOT * 4);
    float*  pb       = (float*)alloc((size_t)NTOT * 4);
    int*    csr_edges = (int*)alloc((size_t)ETOT * 4);
    int*    csr_start = (int*)alloc((size_t)(NTOT + 1) * 4);

    // 0) CSR (deterministic aggregation order)
    build_csr<<<BGR, NPG, 0, stream>>>(ei, csr_edges, csr_start);

    // 1) s1 = x + agg(x)   (N x 128) -> bufC
    aggregate_add<<<NTOT, DIN, 0, stream>>>(x, ei, csr_edges, csr_start, bufC);

    // 2) z1 = s1 @ W1a + b1a  (N x 512) -> bufA
    gemm_bias<<<dim3(DD2 / 64, NTOT / 64), 256, 0, stream>>>(bufC, W1a, b1a, bufA, NTOT, DD2, DIN);

    // 3) BN(z1) + relu -> bufA (in place)
    bn_stats<<<dim3(2, BN_CHUNKS), 256, 0, stream>>>(bufA, DD2, psum, psumsq);
    bn_finalize<<<2, 256, 0, stream>>>(psum, psumsq, g1a, be1a, DD2, scale, shift);
    bn_apply<<<(NTOT * DD2) / 256, 256, 0, stream>>>(bufA, scale, shift, nullptr, bufA, DD2 - 1, 1);

    // 4) h1 = z1n @ W1b + b1b (N x 256) -> bufB
    gemm_bias<<<dim3(DD / 64, NTOT / 64), 256, 0, stream>>>(bufA, W1b, b1b, bufB, NTOT, DD, DD2);

    // 5) post = relu(BN(h1)) + vemb -> bufB (in place)
    bn_stats<<<dim3(1, BN_CHUNKS), 256, 0, stream>>>(bufB, DD, psum, psumsq);
    bn_finalize<<<1, 256, 0, stream>>>(psum, psumsq, g1, be1, DD, scale, shift);
    bn_apply<<<(NTOT * DD) / 256, 256, 0, stream>>>(bufB, scale, shift, vemb, bufB, DD - 1, 1);

    // 6) s2 = post + agg(post) (N x 256) -> bufC
    aggregate_add<<<NTOT, DD, 0, stream>>>(bufB, ei, csr_edges, csr_start, bufC);

    // 7) z2 = s2 @ W2a + b2a (N x 512) -> bufA
    gemm_bias<<<dim3(DD2 / 64, NTOT / 64), 256, 0, stream>>>(bufC, W2a, b2a, bufA, NTOT, DD2, DD);

    // 8) BN(z2) + relu -> bufA
    bn_stats<<<dim3(2, BN_CHUNKS), 256, 0, stream>>>(bufA, DD2, psum, psumsq);
    bn_finalize<<<2, 256, 0, stream>>>(psum, psumsq, g2a, be2a, DD2, scale, shift);
    bn_apply<<<(NTOT * DD2) / 256, 256, 0, stream>>>(bufA, scale, shift, nullptr, bufA, DD2 - 1, 1);

    // 9) h2 = z2n @ W2b + b2b (N x 256) -> bufC
    gemm_bias<<<dim3(DD / 64, NTOT / 64), 256, 0, stream>>>(bufA, W2b, b2b, bufC, NTOT, DD, DD2);

    // 10) xn = BN(h2) (no relu) -> bufC
    bn_stats<<<dim3(1, BN_CHUNKS), 256, 0, stream>>>(bufC, DD, psum, psumsq);
    bn_finalize<<<1, 256, 0, stream>>>(psum, psumsq, g2, be2, DD, scale, shift);
    bn_apply<<<(NTOT * DD) / 256, 256, 0, stream>>>(bufC, scale, shift, nullptr, bufC, DD - 1, 0);

    // 11) per-node dots, edge scores
    node_dots<<<NTOT / 4, 256, 0, stream>>>(bufC, Wl, pa, pb);
    pred_kernel<<<ETOT / 256, 256, 0, stream>>>(pa, pb, ei, bl, out + OFF_PRED);

    // 12) per-graph stable sort + gathers
    sort_write<<<BGR, EPG, 0, stream>>>(out + OFF_PRED, ei, out);
}

// Round 2
// 542.738 us; speedup vs baseline: 1.5908x; 1.5908x over previous
//
#include <hip/hip_runtime.h>

// Problem constants
#define BGR   256      // graphs
#define NPG   128      // nodes per graph
#define EPG   512      // edges per graph
#define DIN   128
#define DD    256
#define DD2   512
#define NTOT  (BGR * NPG)   // 32768
#define ETOT  (BGR * EPG)   // 131072
#define NRES  (EPG / 2)     // 256
#define BN_CHUNKS 128
#define BN_ROWS_PER_CHUNK 256

// Output layout (floats)
#define OFF_CEI  0
#define OFF_CW   (2 * BGR * NRES)
#define OFF_FEI  (OFF_CW + BGR * NRES)
#define OFF_FW   (OFF_FEI + 2 * BGR * NRES)
#define OFF_PRED (OFF_FW + BGR * NRES)

typedef unsigned short ushortt;
typedef __attribute__((ext_vector_type(8))) short short8;
typedef __attribute__((ext_vector_type(4))) float f32x4;

__device__ __forceinline__ ushortt f2bf(float f) {
    unsigned int u = __float_as_uint(f);
    unsigned int r = (u + 0x7fffu + ((u >> 16) & 1u)) >> 16;
    return (ushortt)r;
}
__device__ __forceinline__ float bf2f(ushortt u) {
    return __uint_as_float(((unsigned int)u) << 16);
}

__device__ __forceinline__ void g2lds16(const void* g, void* l) {
    __builtin_amdgcn_global_load_lds(
        (const __attribute__((address_space(1))) unsigned int*)g,
        (__attribute__((address_space(3))) unsigned int*)l, 16, 0, 0);
}

// ---------------------------------------------------------------------------
// Weight convert + transpose: Wt[n][k] = bf16(W[k][n])  (tiny, once per launch)
__global__ __launch_bounds__(256) void convert_wt(const float* __restrict__ W,
                                                  ushortt* __restrict__ Wt,
                                                  int K, int N) {
    const int idx = blockIdx.x * 256 + threadIdx.x;
    if (idx >= K * N) return;
    const int k = idx / N, n = idx % N;
    Wt[(size_t)n * K + k] = f2bf(W[idx]);
}

// ---------------------------------------------------------------------------
// CSR build (stable in edge order).
__global__ __launch_bounds__(NPG) void build_csr(const int* __restrict__ ei,
                                                 int* __restrict__ csr_edges,
                                                 int* __restrict__ csr_start) {
    const int b = blockIdx.x;
    __shared__ int dstl[EPG];
    __shared__ int cnts[NPG];
    const int* col = ei + ETOT + b * EPG;
    for (int i = threadIdx.x; i < EPG; i += NPG) dstl[i] = col[i] - b * NPG;
    __syncthreads();
    const int node = threadIdx.x;
    int cnt = 0;
    for (int e = 0; e < EPG; ++e) cnt += (dstl[e] == node);
    cnts[node] = cnt;
    __syncthreads();
    int start = 0;
    for (int k = 0; k < node; ++k) start += cnts[k];
    csr_start[b * NPG + node] = b * EPG + start;
    if (b == 0 && node == 0) csr_start[NTOT] = ETOT;
    int kk = b * EPG + start;
    for (int e = 0; e < EPG; ++e)
        if (dstl[e] == node) csr_edges[kk++] = b * EPG + e;
}

// ---------------------------------------------------------------------------
// s = h + segment_sum(h[row])  ->  bf16 out.  fp32 input variant (layer 1).
__global__ void aggregate_f32(const float* __restrict__ h,
                              const int* __restrict__ rowidx,
                              const int* __restrict__ csr_edges,
                              const int* __restrict__ csr_start,
                              ushortt* __restrict__ outp) {
    const int i = blockIdx.x;
    const int ncols = blockDim.x;
    const int t = threadIdx.x;
    float acc = h[(size_t)i * ncols + t];
    const int s = csr_start[i], e2 = csr_start[i + 1];
    for (int p = s; p < e2; ++p) {
        const int r = rowidx[csr_edges[p]];
        acc += h[(size_t)r * ncols + t];
    }
    outp[(size_t)i * ncols + t] = f2bf(acc);
}

// bf16 input variant (layer 2).
__global__ void aggregate_bf16(const ushortt* __restrict__ h,
                               const int* __restrict__ rowidx,
                               const int* __restrict__ csr_edges,
                               const int* __restrict__ csr_start,
                               ushortt* __restrict__ outp) {
    const int i = blockIdx.x;
    const int ncols = blockDim.x;
    const int t = threadIdx.x;
    float acc = bf2f(h[(size_t)i * ncols + t]);
    const int s = csr_start[i], e2 = csr_start[i + 1];
    for (int p = s; p < e2; ++p) {
        const int r = rowidx[csr_edges[p]];
        acc += bf2f(h[(size_t)r * ncols + t]);
    }
    outp[(size_t)i * ncols + t] = f2bf(acc);
}

// ---------------------------------------------------------------------------
// bf16 MFMA GEMM (m97 structure): C[M,N] = A[M,K] @ Wt[N,K]^T + bias, fp32 out.
// 128x128 tile, BK=32, 256 threads (4 waves, each 64x64), global_load_lds x16.
#define BM 128
#define BN 128
#define BK 32
__global__ __launch_bounds__(256) void gemm_mfma(const ushortt* __restrict__ A,
                                                 const ushortt* __restrict__ Wt,
                                                 const float* __restrict__ bias,
                                                 float* __restrict__ C,
                                                 int M, int N, int K) {
    __shared__ ushortt As[BM * BK];   // [row][k], row-major, 8 KB
    __shared__ ushortt Bs[BN * BK];   // [col][k], row-major, 8 KB
    const int tid  = threadIdx.x;
    const int wave = tid >> 6;
    const int lane = tid & 63;
    const int q = lane >> 4;          // 0..3
    const int r = lane & 15;          // 0..15
    const int wm = (wave >> 1) * 64;  // wave row offset in tile
    const int wn = (wave & 1) * 64;   // wave col offset in tile
    const int m0 = blockIdx.y * BM;
    const int n0 = blockIdx.x * BN;

    f32x4 acc[4][4] = {};

    for (int k0 = 0; k0 < K; k0 += BK) {
#pragma unroll
        for (int s = 0; s < 2; ++s) {
            const int o   = wave * 128 + s * 64 + lane;  // 16B chunk id, 0..511
            const int row = o >> 2;
            const int cg  = o & 3;
            g2lds16(A  + (size_t)(m0 + row) * K + k0 + cg * 8,
                    &As[(size_t)(wave * 128 + s * 64) * 8]);
            g2lds16(Wt + (size_t)(n0 + row) * K + k0 + cg * 8,
                    &Bs[(size_t)(wave * 128 + s * 64) * 8]);
        }
        __syncthreads();
        short8 af[4], bf[4];
#pragma unroll
        for (int i = 0; i < 4; ++i)
            af[i] = *(const short8*)&As[(wm + i * 16 + r) * BK + q * 8];
#pragma unroll
        for (int j = 0; j < 4; ++j)
            bf[j] = *(const short8*)&Bs[(wn + j * 16 + r) * BK + q * 8];
#pragma unroll
        for (int i = 0; i < 4; ++i)
#pragma unroll
            for (int j = 0; j < 4; ++j)
                acc[i][j] = __builtin_amdgcn_mfma_f32_16x16x32_bf16(af[i], bf[j], acc[i][j], 0, 0, 0);
        __syncthreads();
    }

#pragma unroll
    for (int j = 0; j < 4; ++j) {
        const int col = n0 + wn + j * 16 + r;
        const float bv = bias[col];
#pragma unroll
        for (int i = 0; i < 4; ++i) {
#pragma unroll
            for (int t = 0; t < 4; ++t) {
                const int rowg = m0 + wm + i * 16 + q * 4 + t;
                C[(size_t)rowg * N + col] = acc[i][j][t] + bv;
            }
        }
    }
}

// ---------------------------------------------------------------------------
// BN statistics (deterministic fixed-order fp64 partials).
__global__ __launch_bounds__(256) void bn_stats(const float* __restrict__ z, int ncols,
                                                double* __restrict__ psum,
                                                double* __restrict__ psumsq) {
    const int c = blockIdx.x * 256 + threadIdx.x;
    const int r0 = blockIdx.y * BN_ROWS_PER_CHUNK;
    double s = 0.0, s2 = 0.0;
    const float* p = z + (size_t)r0 * ncols + c;
    for (int r = 0; r < BN_ROWS_PER_CHUNK; ++r) {
        const double v = (double)p[(size_t)r * ncols];
        s += v;
        s2 += v * v;
    }
    psum[(size_t)blockIdx.y * ncols + c] = s;
    psumsq[(size_t)blockIdx.y * ncols + c] = s2;
}

__global__ __launch_bounds__(256) void bn_finalize(const double* __restrict__ psum,
                                                   const double* __restrict__ psumsq,
                                                   const float* __restrict__ g,
                                                   const float* __restrict__ be,
                                                   int ncols,
                                                   float* __restrict__ scale,
                                                   float* __restrict__ shift) {
    const int c = blockIdx.x * 256 + threadIdx.x;
    double s = 0.0, s2 = 0.0;
    for (int k = 0; k < BN_CHUNKS; ++k) {
        s += psum[(size_t)k * ncols + c];
        s2 += psumsq[(size_t)k * ncols + c];
    }
    const double mean = s / (double)NTOT;
    const double var = s2 / (double)NTOT - mean * mean;
    const double rs = 1.0 / sqrt(var + 1e-5);
    const float sc = (float)((double)g[c] * rs);
    scale[c] = sc;
    shift[c] = (float)((double)be[c] - mean * (double)sc);
}

// out_bf16 = bf16( relu(z*scale+shift) [+ vadd] )
__global__ __launch_bounds__(256) void bn_apply_bf16(const float* __restrict__ z,
                                                     const float* __restrict__ scale,
                                                     const float* __restrict__ shift,
                                                     const float* __restrict__ vadd,
                                                     ushortt* __restrict__ outp,
                                                     int ncolmask) {
    const size_t idx = (size_t)blockIdx.x * 256 + threadIdx.x;
    const int c = (int)(idx & (size_t)ncolmask);
    float v = fmaf(z[idx], scale[c], shift[c]);
    v = fmaxf(v, 0.0f);
    if (vadd) v += vadd[c];
    outp[idx] = f2bf(v);
}

// out_f32 = z*scale+shift (no relu) — final xn, in place
__global__ __launch_bounds__(256) void bn_apply_f32(const float* __restrict__ z,
                                                    const float* __restrict__ scale,
                                                    const float* __restrict__ shift,
                                                    float* __restrict__ outp,
                                                    int ncolmask) {
    const size_t idx = (size_t)blockIdx.x * 256 + threadIdx.x;
    const int c = (int)(idx & (size_t)ncolmask);
    outp[idx] = fmaf(z[idx], scale[c], shift[c]);
}

// ---------------------------------------------------------------------------
__global__ __launch_bounds__(256) void node_dots(const float* __restrict__ xn,
                                                 const float* __restrict__ Wl,
                                                 float* __restrict__ pa,
                                                 float* __restrict__ pb) {
    const int wave = threadIdx.x >> 6;
    const int lane = threadIdx.x & 63;
    const int node = blockIdx.x * 4 + wave;
    const float* xr = xn + (size_t)node * DD;
    float sa = 0.0f, sb = 0.0f;
#pragma unroll
    for (int c0 = 0; c0 < DD; c0 += 64) {
        const int c = c0 + lane;
        const float v = xr[c];
        sa = fmaf(v, Wl[c], sa);
        sb = fmaf(v, Wl[DD + c], sb);
    }
#pragma unroll
    for (int off = 32; off >= 1; off >>= 1) {
        sa += __shfl_down(sa, off);
        sb += __shfl_down(sb, off);
    }
    if (lane == 0) {
        pa[node] = sa;
        pb[node] = sb;
    }
}

__global__ __launch_bounds__(256) void pred_kernel(const float* __restrict__ pa,
                                                   const float* __restrict__ pb,
                                                   const int* __restrict__ ei,
                                                   const float* __restrict__ bl,
                                                   float* __restrict__ pred) {
    const int e = blockIdx.x * 256 + threadIdx.x;
    const int r = ei[e];
    const int c = ei[ETOT + e];
    pred[e] = pa[r] + pb[c] + bl[0];
}

// ---------------------------------------------------------------------------
__global__ __launch_bounds__(EPG) void sort_write(const float* __restrict__ pred,
                                                  const int* __restrict__ ei,
                                                  float* __restrict__ out) {
    __shared__ float pw[EPG];
    __shared__ int ord[EPG];
    const int b = blockIdx.x;
    const int t = threadIdx.x;
    const float v = pred[b * EPG + t];
    pw[t] = v;
    __syncthreads();
    int rank = 0;
    for (int k = 0; k < EPG; ++k) {
        const float u = pw[k];
        rank += (u > v) || (u == v && k < t);
    }
    ord[rank] = t;
    __syncthreads();
    const int j = ord[t];
    const float wv = pw[j];
    const float e0 = (float)ei[b * EPG + j];
    const float e1 = (float)ei[ETOT + b * EPG + j];
    if (t < NRES) {
        out[OFF_CEI + b * NRES + t] = e0;
        out[OFF_CEI + BGR * NRES + b * NRES + t] = e1;
        out[OFF_CW + b * NRES + t] = wv;
    } else {
        const int p = t - NRES;
        out[OFF_FEI + b * NRES + p] = e0;
        out[OFF_FEI + BGR * NRES + b * NRES + p] = e1;
        out[OFF_FW + b * NRES + p] = -wv;
    }
}

// ---------------------------------------------------------------------------
extern "C" void kernel_launch(void* const* d_in, const int* in_sizes, int n_in,
                              void* d_out, int out_size, void* d_ws, size_t ws_size,
                              hipStream_t stream) {
    (void)in_sizes; (void)n_in; (void)out_size; (void)ws_size;
    const float* x    = (const float*)d_in[0];
    const int*   ei   = (const int*)d_in[1];
    const float* vemb = (const float*)d_in[3];
    const float* W1a  = (const float*)d_in[4];
    const float* b1a  = (const float*)d_in[5];
    const float* g1a  = (const float*)d_in[6];
    const float* be1a = (const float*)d_in[7];
    const float* W1b  = (const float*)d_in[8];
    const float* b1b  = (const float*)d_in[9];
    const float* g1   = (const float*)d_in[10];
    const float* be1  = (const float*)d_in[11];
    const float* W2a  = (const float*)d_in[12];
    const float* b2a  = (const float*)d_in[13];
    const float* g2a  = (const float*)d_in[14];
    const float* be2a = (const float*)d_in[15];
    const float* W2b  = (const float*)d_in[16];
    const float* b2b  = (const float*)d_in[17];
    const float* g2   = (const float*)d_in[18];
    const float* be2  = (const float*)d_in[19];
    const float* Wl   = (const float*)d_in[20];
    const float* bl   = (const float*)d_in[21];
    float* out = (float*)d_out;

    // workspace carve-up (~116 MB)
    char* wp = (char*)d_ws;
    auto alloc = [&](size_t bytes) -> char* {
        char* r = wp;
        wp += (bytes + 255) & ~(size_t)255;
        return r;
    };
    float*    zf    = (float*)alloc((size_t)NTOT * 512 * 4);   // 64MB: z1,h1,z2,h2,xn
    ushortt*  bufC  = (ushortt*)alloc((size_t)NTOT * 512 * 2); // 32MB: z1n, s2, z2n
    ushortt*  bufD  = (ushortt*)alloc((size_t)NTOT * 256 * 2); // 16MB: s1, post
    ushortt*  Wt1a  = (ushortt*)alloc((size_t)DIN * DD2 * 2);
    ushortt*  Wt1b  = (ushortt*)alloc((size_t)DD2 * DD * 2);
    ushortt*  Wt2a  = (ushortt*)alloc((size_t)DD * DD2 * 2);
    ushortt*  Wt2b  = (ushortt*)alloc((size_t)DD2 * DD * 2);
    double*   psum   = (double*)alloc((size_t)BN_CHUNKS * 512 * 8);
    double*   psumsq = (double*)alloc((size_t)BN_CHUNKS * 512 * 8);
    float*    scale  = (float*)alloc(512 * 4);
    float*    shift  = (float*)alloc(512 * 4);
    float*    pa     = (float*)alloc((size_t)NTOT * 4);
    float*    pb     = (float*)alloc((size_t)NTOT * 4);
    int*      csr_edges = (int*)alloc((size_t)ETOT * 4);
    int*      csr_start = (int*)alloc((size_t)(NTOT + 1) * 4);

    // weights -> bf16, transposed [N][K]
    convert_wt<<<(DIN * DD2 + 255) / 256, 256, 0, stream>>>(W1a, Wt1a, DIN, DD2);
    convert_wt<<<(DD2 * DD + 255) / 256, 256, 0, stream>>>(W1b, Wt1b, DD2, DD);
    convert_wt<<<(DD * DD2 + 255) / 256, 256, 0, stream>>>(W2a, Wt2a, DD, DD2);
    convert_wt<<<(DD2 * DD + 255) / 256, 256, 0, stream>>>(W2b, Wt2b, DD2, DD);

    build_csr<<<BGR, NPG, 0, stream>>>(ei, csr_edges, csr_start);

    // 1) s1 = x + agg(x)  (N x 128, bf16) -> bufD
    aggregate_f32<<<NTOT, DIN, 0, stream>>>(x, ei, csr_edges, csr_start, bufD);

    // 2) z1 = s1 @ W1a + b1a (N x 512, fp32) -> zf
    gemm_mfma<<<dim3(DD2 / BN, NTOT / BM), 256, 0, stream>>>(bufD, Wt1a, b1a, zf, NTOT, DD2, DIN);

    // 3) z1n = bf16(relu(BN(z1))) -> bufC
    bn_stats<<<dim3(2, BN_CHUNKS), 256, 0, stream>>>(zf, DD2, psum, psumsq);
    bn_finalize<<<2, 256, 0, stream>>>(psum, psumsq, g1a, be1a, DD2, scale, shift);
    bn_apply_bf16<<<(NTOT * DD2) / 256, 256, 0, stream>>>(zf, scale, shift, nullptr, bufC, DD2 - 1);

    // 4) h1 = z1n @ W1b + b1b (N x 256, fp32) -> zf
    gemm_mfma<<<dim3(DD / BN, NTOT / BM), 256, 0, stream>>>(bufC, Wt1b, b1b, zf, NTOT, DD, DD2);

    // 5) post = bf16(relu(BN(h1)) + vemb) -> bufD
    bn_stats<<<dim3(1, BN_CHUNKS), 256, 0, stream>>>(zf, DD, psum, psumsq);
    bn_finalize<<<1, 256, 0, stream>>>(psum, psumsq, g1, be1, DD, scale, shift);
    bn_apply_bf16<<<(NTOT * DD) / 256, 256, 0, stream>>>(zf, scale, shift, vemb, bufD, DD - 1);

    // 6) s2 = post + agg(post) (N x 256, bf16) -> bufC
    aggregate_bf16<<<NTOT, DD, 0, stream>>>(bufD, ei, csr_edges, csr_start, bufC);

    // 7) z2 = s2 @ W2a + b2a (N x 512, fp32) -> zf
    gemm_mfma<<<dim3(DD2 / BN, NTOT / BM), 256, 0, stream>>>(bufC, Wt2a, b2a, zf, NTOT, DD2, DD);

    // 8) z2n = bf16(relu(BN(z2))) -> bufC
    bn_stats<<<dim3(2, BN_CHUNKS), 256, 0, stream>>>(zf, DD2, psum, psumsq);
    bn_finalize<<<2, 256, 0, stream>>>(psum, psumsq, g2a, be2a, DD2, scale, shift);
    bn_apply_bf16<<<(NTOT * DD2) / 256, 256, 0, stream>>>(zf, scale, shift, nullptr, bufC, DD2 - 1);

    // 9) h2 = z2n @ W2b + b2b (N x 256, fp32) -> zf
    gemm_mfma<<<dim3(DD / BN, NTOT / BM), 256, 0, stream>>>(bufC, Wt2b, b2b, zf, NTOT, DD, DD2);

    // 10) xn = BN(h2) (no relu, fp32) -> zf in place
    bn_stats<<<dim3(1, BN_CHUNKS), 256, 0, stream>>>(zf, DD, psum, psumsq);
    bn_finalize<<<1, 256, 0, stream>>>(psum, psumsq, g2, be2, DD, scale, shift);
    bn_apply_f32<<<(NTOT * DD) / 256, 256, 0, stream>>>(zf, scale, shift, zf, DD - 1);

    // 11) per-node dots, edge scores
    node_dots<<<NTOT / 4, 256, 0, stream>>>(zf, Wl, pa, pb);
    pred_kernel<<<ETOT / 256, 256, 0, stream>>>(pa, pb, ei, bl, out + OFF_PRED);

    // 12) per-graph stable sort + gathers
    sort_write<<<BGR, EPG, 0, stream>>>(out + OFF_PRED, ei, out);
}

// Round 3
// 441.172 us; speedup vs baseline: 1.9571x; 1.2302x over previous
//
#include <hip/hip_runtime.h>

// Problem constants
#define BGR   256
#define NPG   128
#define EPG   512
#define DIN   128
#define DD    256
#define DD2   512
#define NTOT  (BGR * NPG)   // 32768
#define ETOT  (BGR * EPG)   // 131072
#define NRES  (EPG / 2)
#define NCHUNK 256          // M / BM row-chunks for BN partials

// Output layout (floats)
#define OFF_CEI  0
#define OFF_CW   (2 * BGR * NRES)
#define OFF_FEI  (OFF_CW + BGR * NRES)
#define OFF_FW   (OFF_FEI + 2 * BGR * NRES)
#define OFF_PRED (OFF_FW + BGR * NRES)

typedef unsigned short ushortt;
typedef __attribute__((ext_vector_type(4))) unsigned short us4;
typedef __attribute__((ext_vector_type(8))) short short8;
typedef __attribute__((ext_vector_type(4))) float f32x4;

__device__ __forceinline__ ushortt f2bf(float f) {
    unsigned int u = __float_as_uint(f);
    unsigned int r = (u + 0x7fffu + ((u >> 16) & 1u)) >> 16;
    return (ushortt)r;
}
__device__ __forceinline__ float bf2f(ushortt u) {
    return __uint_as_float(((unsigned int)u) << 16);
}

__device__ __forceinline__ void g2lds16(const void* g, void* l) {
    __builtin_amdgcn_global_load_lds(
        (const __attribute__((address_space(1))) unsigned int*)g,
        (__attribute__((address_space(3))) unsigned int*)l, 16, 0, 0);
}

// ---------------------------------------------------------------------------
__global__ __launch_bounds__(256) void convert_wt(const float* __restrict__ W,
                                                  ushortt* __restrict__ Wt,
                                                  int K, int N) {
    const int idx = blockIdx.x * 256 + threadIdx.x;
    if (idx >= K * N) return;
    const int k = idx / N, n = idx % N;
    Wt[(size_t)n * K + k] = f2bf(W[idx]);
}

// ---------------------------------------------------------------------------
// CSR build: stable in edge order; stores LOCAL src ids per slot.
__global__ __launch_bounds__(NPG) void build_csr(const int* __restrict__ ei,
                                                 int* __restrict__ csr_src,
                                                 int* __restrict__ csr_start) {
    const int b = blockIdx.x;
    __shared__ int dstl[EPG];
    __shared__ int srcl[EPG];
    __shared__ int cnts[NPG];
    const int* rowg = ei + b * EPG;
    const int* colg = ei + ETOT + b * EPG;
    for (int i = threadIdx.x; i < EPG; i += NPG) {
        dstl[i] = colg[i] - b * NPG;
        srcl[i] = rowg[i] - b * NPG;
    }
    __syncthreads();
    const int node = threadIdx.x;
    int cnt = 0;
    for (int e = 0; e < EPG; ++e) cnt += (dstl[e] == node);
    cnts[node] = cnt;
    __syncthreads();
    int start = 0;
    for (int k = 0; k < node; ++k) start += cnts[k];
    csr_start[b * NPG + node] = b * EPG + start;
    if (b == 0 && node == 0) csr_start[NTOT] = ETOT;
    int kk = b * EPG + start;
    for (int e = 0; e < EPG; ++e)
        if (dstl[e] == node) csr_src[kk++] = srcl[e];
}

// ---------------------------------------------------------------------------
// Layer-1 aggregate: s1 = bf16(x + agg(x)), per-graph LDS staged. x fp32 Nx128.
__global__ __launch_bounds__(256) void agg1(const float* __restrict__ x,
                                            const int* __restrict__ csr_src,
                                            const int* __restrict__ csr_start,
                                            ushortt* __restrict__ outp) {
    __shared__ float hx[NPG * DIN];     // 64 KB
    __shared__ int sstart[NPG + 1];
    __shared__ int ssrc[EPG];
    const int b = blockIdx.x;
    const int t = threadIdx.x;
    const float4* xg = (const float4*)(x + (size_t)b * NPG * DIN);
    float4* hx4 = (float4*)hx;
    for (int i = t; i < NPG * DIN / 4; i += 256) hx4[i] = xg[i];
    if (t < NPG + 1) sstart[t] = csr_start[b * NPG + t] - b * EPG;
    for (int i = t; i < EPG; i += 256) ssrc[i] = csr_src[b * EPG + i];
    __syncthreads();
    const int cg = t & 31;          // 32 col-groups of 4 (f32)
    const int rsub = t >> 5;        // 0..7
    for (int row = rsub; row < NPG; row += 8) {
        float4 acc = *(const float4*)&hx[row * DIN + cg * 4];
        const int s = sstart[row], e = sstart[row + 1];
        for (int p = s; p < e; ++p) {
            const float4 nb = *(const float4*)&hx[ssrc[p] * DIN + cg * 4];
            acc.x += nb.x; acc.y += nb.y; acc.z += nb.z; acc.w += nb.w;
        }
        us4 o = { f2bf(acc.x), f2bf(acc.y), f2bf(acc.z), f2bf(acc.w) };
        *(us4*)&outp[(size_t)(b * NPG + row) * DIN + cg * 4] = o;
    }
}

// ---------------------------------------------------------------------------
// Layer-2 aggregate, FUSED with BN-apply+relu+vemb on staging:
// post = bf16(relu(h*scale+shift) + vemb);  s2 = bf16(post + agg(post))
__global__ __launch_bounds__(256) void agg2(const ushortt* __restrict__ h,
                                            const float* __restrict__ scale,
                                            const float* __restrict__ shift,
                                            const float* __restrict__ vemb,
                                            const int* __restrict__ csr_src,
                                            const int* __restrict__ csr_start,
                                            ushortt* __restrict__ outp) {
    __shared__ ushortt hp[NPG * DD];    // 64 KB
    __shared__ int sstart[NPG + 1];
    __shared__ int ssrc[EPG];
    const int b = blockIdx.x;
    const int t = threadIdx.x;
    const us4* zg = (const us4*)(h + (size_t)b * NPG * DD);
    us4* hp4 = (us4*)hp;
    for (int i = t; i < NPG * DD / 4; i += 256) {
        const us4 z4 = zg[i];
        const int c0 = (i & (DD / 4 - 1)) * 4;
        us4 o;
#pragma unroll
        for (int e = 0; e < 4; ++e) {
            float v = fmaf(bf2f(z4[e]), scale[c0 + e], shift[c0 + e]);
            v = fmaxf(v, 0.0f) + vemb[c0 + e];
            o[e] = f2bf(v);
        }
        hp4[i] = o;
    }
    if (t < NPG + 1) sstart[t] = csr_start[b * NPG + t] - b * EPG;
    for (int i = t; i < EPG; i += 256) ssrc[i] = csr_src[b * EPG + i];
    __syncthreads();
    const int cg = t & 63;          // 64 col-groups of 4 (bf16)
    const int rsub = t >> 6;        // 0..3 (wave-uniform row!)
    for (int row = rsub; row < NPG; row += 4) {
        const us4 own = *(const us4*)&hp[row * DD + cg * 4];
        float4 acc = { bf2f(own.x), bf2f(own.y), bf2f(own.z), bf2f(own.w) };
        const int s = sstart[row], e = sstart[row + 1];
        for (int p = s; p < e; ++p) {
            const us4 nb = *(const us4*)&hp[ssrc[p] * DD + cg * 4];
            acc.x += bf2f(nb.x); acc.y += bf2f(nb.y);
            acc.z += bf2f(nb.z); acc.w += bf2f(nb.w);
        }
        us4 o = { f2bf(acc.x), f2bf(acc.y), f2bf(acc.z), f2bf(acc.w) };
        *(us4*)&outp[(size_t)(b * NPG + row) * DD + cg * 4] = o;
    }
}

// ---------------------------------------------------------------------------
// bf16 MFMA GEMM, 128x128 tile, BK=32, 4 waves. Outputs bf16 C = A@Wt^T + bias
// and fp64 per-column partial sums/sumsq over this block's 128 rows (BN stats
// fused — deterministic fixed-order reduction).
#define BM 128
#define BN 128
#define BK 32
__global__ __launch_bounds__(256) void gemm_mfma(const ushortt* __restrict__ A,
                                                 const ushortt* __restrict__ Wt,
                                                 const float* __restrict__ bias,
                                                 ushortt* __restrict__ C,
                                                 double* __restrict__ psum,
                                                 double* __restrict__ psumsq,
                                                 int M, int N, int K) {
    __shared__ ushortt As[BM * BK];
    __shared__ ushortt Bs[BN * BK];
    __shared__ double redS[2][BN];
    __shared__ double redQ[2][BN];
    const int tid  = threadIdx.x;
    const int wave = tid >> 6;
    const int lane = tid & 63;
    const int qd = lane >> 4;
    const int r  = lane & 15;
    const int wm = (wave >> 1) * 64;
    const int wn = (wave & 1) * 64;
    const int m0 = blockIdx.y * BM;
    const int n0 = blockIdx.x * BN;

    f32x4 acc[4][4] = {};

    for (int k0 = 0; k0 < K; k0 += BK) {
#pragma unroll
        for (int s = 0; s < 2; ++s) {
            const int o   = wave * 128 + s * 64 + lane;
            const int row = o >> 2;
            const int cg  = o & 3;
            g2lds16(A  + (size_t)(m0 + row) * K + k0 + cg * 8,
                    &As[(size_t)(wave * 128 + s * 64) * 8]);
            g2lds16(Wt + (size_t)(n0 + row) * K + k0 + cg * 8,
                    &Bs[(size_t)(wave * 128 + s * 64) * 8]);
        }
        __syncthreads();
        short8 af[4], bfr[4];
#pragma unroll
        for (int i = 0; i < 4; ++i)
            af[i] = *(const short8*)&As[(wm + i * 16 + r) * BK + qd * 8];
#pragma unroll
        for (int j = 0; j < 4; ++j)
            bfr[j] = *(const short8*)&Bs[(wn + j * 16 + r) * BK + qd * 8];
#pragma unroll
        for (int i = 0; i < 4; ++i)
#pragma unroll
            for (int j = 0; j < 4; ++j)
                acc[i][j] = __builtin_amdgcn_mfma_f32_16x16x32_bf16(af[i], bfr[j], acc[i][j], 0, 0, 0);
        __syncthreads();
    }

    // Epilogue: bias add, bf16 store, fp64 column partials.
#pragma unroll
    for (int j = 0; j < 4; ++j) {
        const int coll = wn + j * 16 + r;
        const int col  = n0 + coll;
        const float bv = bias[col];
        double s = 0.0, q = 0.0;
#pragma unroll
        for (int i = 0; i < 4; ++i) {
#pragma unroll
            for (int t = 0; t < 4; ++t) {
                const float v = acc[i][j][t] + bv;
                C[(size_t)(m0 + wm + i * 16 + qd * 4 + t) * N + col] = f2bf(v);
                s += (double)v;
                q += (double)v * (double)v;
            }
        }
        s += __shfl_xor(s, 16); s += __shfl_xor(s, 32);
        q += __shfl_xor(q, 16); q += __shfl_xor(q, 32);
        if (qd == 0) {
            redS[wave >> 1][coll] = s;
            redQ[wave >> 1][coll] = q;
        }
    }
    __syncthreads();
    if (tid < BN) {
        psum[(size_t)blockIdx.y * N + n0 + tid]   = redS[0][tid] + redS[1][tid];
        psumsq[(size_t)blockIdx.y * N + n0 + tid] = redQ[0][tid] + redQ[1][tid];
    }
}

// ---------------------------------------------------------------------------
__global__ __launch_bounds__(256) void bn_finalize(const double* __restrict__ psum,
                                                   const double* __restrict__ psumsq,
                                                   const float* __restrict__ g,
                                                   const float* __restrict__ be,
                                                   int ncols,
                                                   float* __restrict__ scale,
                                                   float* __restrict__ shift) {
    const int c = blockIdx.x * 256 + threadIdx.x;
    double s = 0.0, s2 = 0.0;
    for (int k = 0; k < NCHUNK; ++k) {
        s += psum[(size_t)k * ncols + c];
        s2 += psumsq[(size_t)k * ncols + c];
    }
    const double mean = s / (double)NTOT;
    const double var = s2 / (double)NTOT - mean * mean;
    const double rs = 1.0 / sqrt(var + 1e-5);
    const float sc = (float)((double)g[c] * rs);
    scale[c] = sc;
    shift[c] = (float)((double)be[c] - mean * (double)sc);
}

// out = bf16( [relu](z*scale+shift) ), vectorized x4, bf16 in/out
__global__ __launch_bounds__(256) void bn_apply_vec(const ushortt* __restrict__ z,
                                                    const float* __restrict__ scale,
                                                    const float* __restrict__ shift,
                                                    ushortt* __restrict__ outp,
                                                    int ncolmask, int relu) {
    const size_t gi = (size_t)blockIdx.x * 256 + threadIdx.x;
    const int c0 = (int)((gi * 4) & (size_t)ncolmask);
    const us4 z4 = *(const us4*)&z[gi * 4];
    us4 o;
#pragma unroll
    for (int e = 0; e < 4; ++e) {
        float v = fmaf(bf2f(z4[e]), scale[c0 + e], shift[c0 + e]);
        if (relu) v = fmaxf(v, 0.0f);
        o[e] = f2bf(v);
    }
    *(us4*)&outp[gi * 4] = o;
}

// ---------------------------------------------------------------------------
__global__ __launch_bounds__(256) void node_dots(const ushortt* __restrict__ xn,
                                                 const float* __restrict__ Wl,
                                                 float* __restrict__ pa,
                                                 float* __restrict__ pb) {
    const int wave = threadIdx.x >> 6;
    const int lane = threadIdx.x & 63;
    const int node = blockIdx.x * 4 + wave;
    const us4 xv = *(const us4*)&xn[(size_t)node * DD + lane * 4];
    const float4 w0 = *(const float4*)&Wl[lane * 4];
    const float4 w1 = *(const float4*)&Wl[DD + lane * 4];
    const float x0 = bf2f(xv.x), x1 = bf2f(xv.y), x2 = bf2f(xv.z), x3 = bf2f(xv.w);
    float sa = x0 * w0.x + x1 * w0.y + x2 * w0.z + x3 * w0.w;
    float sb = x0 * w1.x + x1 * w1.y + x2 * w1.z + x3 * w1.w;
#pragma unroll
    for (int off = 32; off >= 1; off >>= 1) {
        sa += __shfl_down(sa, off);
        sb += __shfl_down(sb, off);
    }
    if (lane == 0) {
        pa[node] = sa;
        pb[node] = sb;
    }
}

__global__ __launch_bounds__(256) void pred_kernel(const float* __restrict__ pa,
                                                   const float* __restrict__ pb,
                                                   const int* __restrict__ ei,
                                                   const float* __restrict__ bl,
                                                   float* __restrict__ pred) {
    const int e = blockIdx.x * 256 + threadIdx.x;
    const int r = ei[e];
    const int c = ei[ETOT + e];
    pred[e] = pa[r] + pb[c] + bl[0];
}

// ---------------------------------------------------------------------------
__global__ __launch_bounds__(EPG) void sort_write(const float* __restrict__ pred,
                                                  const int* __restrict__ ei,
                                                  float* __restrict__ out) {
    __shared__ float pw[EPG];
    __shared__ int ord[EPG];
    const int b = blockIdx.x;
    const int t = threadIdx.x;
    const float v = pred[b * EPG + t];
    pw[t] = v;
    __syncthreads();
    int rank = 0;
    for (int k = 0; k < EPG; ++k) {
        const float u = pw[k];
        rank += (u > v) || (u == v && k < t);
    }
    ord[rank] = t;
    __syncthreads();
    const int j = ord[t];
    const float wv = pw[j];
    const float e0 = (float)ei[b * EPG + j];
    const float e1 = (float)ei[ETOT + b * EPG + j];
    if (t < NRES) {
        out[OFF_CEI + b * NRES + t] = e0;
        out[OFF_CEI + BGR * NRES + b * NRES + t] = e1;
        out[OFF_CW + b * NRES + t] = wv;
    } else {
        const int p = t - NRES;
        out[OFF_FEI + b * NRES + p] = e0;
        out[OFF_FEI + BGR * NRES + b * NRES + p] = e1;
        out[OFF_FW + b * NRES + p] = -wv;
    }
}

// ---------------------------------------------------------------------------
extern "C" void kernel_launch(void* const* d_in, const int* in_sizes, int n_in,
                              void* d_out, int out_size, void* d_ws, size_t ws_size,
                              hipStream_t stream) {
    (void)in_sizes; (void)n_in; (void)out_size; (void)ws_size;
    const float* x    = (const float*)d_in[0];
    const int*   ei   = (const int*)d_in[1];
    const float* vemb = (const float*)d_in[3];
    const float* W1a  = (const float*)d_in[4];
    const float* b1a  = (const float*)d_in[5];
    const float* g1a  = (const float*)d_in[6];
    const float* be1a = (const float*)d_in[7];
    const float* W1b  = (const float*)d_in[8];
    const float* b1b  = (const float*)d_in[9];
    const float* g1   = (const float*)d_in[10];
    const float* be1  = (const float*)d_in[11];
    const float* W2a  = (const float*)d_in[12];
    const float* b2a  = (const float*)d_in[13];
    const float* g2a  = (const float*)d_in[14];
    const float* be2a = (const float*)d_in[15];
    const float* W2b  = (const float*)d_in[16];
    const float* b2b  = (const float*)d_in[17];
    const float* g2   = (const float*)d_in[18];
    const float* be2  = (const float*)d_in[19];
    const float* Wl   = (const float*)d_in[20];
    const float* bl   = (const float*)d_in[21];
    float* out = (float*)d_out;

    char* wp = (char*)d_ws;
    auto alloc = [&](size_t bytes) -> char* {
        char* r = wp;
        wp += (bytes + 255) & ~(size_t)255;
        return r;
    };
    ushortt* zb    = (ushortt*)alloc((size_t)NTOT * 512 * 2);  // z1/h1/z2/h2/xn
    ushortt* bufC  = (ushortt*)alloc((size_t)NTOT * 512 * 2);  // z1n / z2n
    ushortt* bufD  = (ushortt*)alloc((size_t)NTOT * 256 * 2);  // s2
    ushortt* bufS1 = (ushortt*)alloc((size_t)NTOT * 128 * 2);  // s1
    ushortt* Wt1a  = (ushortt*)alloc((size_t)DIN * DD2 * 2);
    ushortt* Wt1b  = (ushortt*)alloc((size_t)DD2 * DD * 2);
    ushortt* Wt2a  = (ushortt*)alloc((size_t)DD * DD2 * 2);
    ushortt* Wt2b  = (ushortt*)alloc((size_t)DD2 * DD * 2);
    double*  psum   = (double*)alloc((size_t)NCHUNK * 512 * 8);
    double*  psumsq = (double*)alloc((size_t)NCHUNK * 512 * 8);
    float*   scale  = (float*)alloc(512 * 4);
    float*   shift  = (float*)alloc(512 * 4);
    float*   pa     = (float*)alloc((size_t)NTOT * 4);
    float*   pb     = (float*)alloc((size_t)NTOT * 4);
    int*     csr_src   = (int*)alloc((size_t)ETOT * 4);
    int*     csr_start = (int*)alloc((size_t)(NTOT + 1) * 4);

    convert_wt<<<(DIN * DD2 + 255) / 256, 256, 0, stream>>>(W1a, Wt1a, DIN, DD2);
    convert_wt<<<(DD2 * DD + 255) / 256, 256, 0, stream>>>(W1b, Wt1b, DD2, DD);
    convert_wt<<<(DD * DD2 + 255) / 256, 256, 0, stream>>>(W2a, Wt2a, DD, DD2);
    convert_wt<<<(DD2 * DD + 255) / 256, 256, 0, stream>>>(W2b, Wt2b, DD2, DD);

    build_csr<<<BGR, NPG, 0, stream>>>(ei, csr_src, csr_start);

    // 1) s1 = bf16(x + agg(x))
    agg1<<<BGR, 256, 0, stream>>>(x, csr_src, csr_start, bufS1);

    // 2) z1 = s1 @ W1a + b1a (bf16) + fused stats
    gemm_mfma<<<dim3(DD2 / BN, NTOT / BM), 256, 0, stream>>>(bufS1, Wt1a, b1a, zb, psum, psumsq, NTOT, DD2, DIN);
    bn_finalize<<<2, 256, 0, stream>>>(psum, psumsq, g1a, be1a, DD2, scale, shift);
    bn_apply_vec<<<(NTOT * DD2) / 1024, 256, 0, stream>>>(zb, scale, shift, bufC, DD2 - 1, 1);

    // 4) h1 = z1n @ W1b + b1b + fused stats
    gemm_mfma<<<dim3(DD / BN, NTOT / BM), 256, 0, stream>>>(bufC, Wt1b, b1b, zb, psum, psumsq, NTOT, DD, DD2);
    bn_finalize<<<1, 256, 0, stream>>>(psum, psumsq, g1, be1, DD, scale, shift);

    // 5+6) s2 = post + agg(post), post = relu(BN(h1)) + vemb fused in staging
    agg2<<<BGR, 256, 0, stream>>>(zb, scale, shift, vemb, csr_src, csr_start, bufD);

    // 7) z2 = s2 @ W2a + b2a + fused stats
    gemm_mfma<<<dim3(DD2 / BN, NTOT / BM), 256, 0, stream>>>(bufD, Wt2a, b2a, zb, psum, psumsq, NTOT, DD2, DD);
    bn_finalize<<<2, 256, 0, stream>>>(psum, psumsq, g2a, be2a, DD2, scale, shift);
    bn_apply_vec<<<(NTOT * DD2) / 1024, 256, 0, stream>>>(zb, scale, shift, bufC, DD2 - 1, 1);

    // 9) h2 = z2n @ W2b + b2b + fused stats
    gemm_mfma<<<dim3(DD / BN, NTOT / BM), 256, 0, stream>>>(bufC, Wt2b, b2b, zb, psum, psumsq, NTOT, DD, DD2);
    bn_finalize<<<1, 256, 0, stream>>>(psum, psumsq, g2, be2, DD, scale, shift);

    // 10) xn = bf16(BN(h2)), in place
    bn_apply_vec<<<(NTOT * DD) / 1024, 256, 0, stream>>>(zb, scale, shift, zb, DD - 1, 0);

    // 11) per-node dots, edge scores
    node_dots<<<NTOT / 4, 256, 0, stream>>>(zb, Wl, pa, pb);
    pred_kernel<<<ETOT / 256, 256, 0, stream>>>(pa, pb, ei, bl, out + OFF_PRED);

    // 12) per-graph stable sort + gathers
    sort_write<<<BGR, EPG, 0, stream>>>(out + OFF_PRED, ei, out);
}

// Round 4
// 426.281 us; speedup vs baseline: 2.0254x; 1.0349x over previous
//
#include <hip/hip_runtime.h>

// Problem constants
#define BGR   256
#define NPG   128
#define EPG   512
#define DIN   128
#define DD    256
#define DD2   512
#define NTOT  (BGR * NPG)   // 32768
#define ETOT  (BGR * EPG)   // 131072
#define NRES  (EPG / 2)
#define NCHUNK 256          // M / BM row-chunks for BN partials

// Output layout (floats)
#define OFF_CEI  0
#define OFF_CW   (2 * BGR * NRES)
#define OFF_FEI  (OFF_CW + BGR * NRES)
#define OFF_FW   (OFF_FEI + 2 * BGR * NRES)
#define OFF_PRED (OFF_FW + BGR * NRES)

typedef unsigned short ushortt;
typedef __attribute__((ext_vector_type(4))) unsigned short us4;
typedef __attribute__((ext_vector_type(8))) unsigned short us8;
typedef __attribute__((ext_vector_type(8))) short short8;
typedef __attribute__((ext_vector_type(4))) float f32x4;

__device__ __forceinline__ ushortt f2bf(float f) {
    unsigned int u = __float_as_uint(f);
    unsigned int r = (u + 0x7fffu + ((u >> 16) & 1u)) >> 16;
    return (ushortt)r;
}
__device__ __forceinline__ float bf2f(ushortt u) {
    return __uint_as_float(((unsigned int)u) << 16);
}

__device__ __forceinline__ void g2lds16(const void* g, void* l) {
    __builtin_amdgcn_global_load_lds(
        (const __attribute__((address_space(1))) unsigned int*)g,
        (__attribute__((address_space(3))) unsigned int*)l, 16, 0, 0);
}

// ---------------------------------------------------------------------------
// All four weight transposes in one dispatch.
__global__ __launch_bounds__(256) void convert_all(const float* __restrict__ W1a,
                                                   const float* __restrict__ W1b,
                                                   const float* __restrict__ W2a,
                                                   const float* __restrict__ W2b,
                                                   ushortt* __restrict__ Wt1a,
                                                   ushortt* __restrict__ Wt1b,
                                                   ushortt* __restrict__ Wt2a,
                                                   ushortt* __restrict__ Wt2b) {
    const int idx = blockIdx.x * 256 + threadIdx.x;
    if (idx < 65536) {                       // W1a: 128x512
        const int k = idx >> 9, n = idx & 511;
        Wt1a[n * DIN + k] = f2bf(W1a[idx]);
    } else if (idx < 196608) {               // W1b: 512x256
        const int i = idx - 65536;
        const int k = i >> 8, n = i & 255;
        Wt1b[n * DD2 + k] = f2bf(W1b[i]);
    } else if (idx < 327680) {               // W2a: 256x512
        const int i = idx - 196608;
        const int k = i >> 9, n = i & 511;
        Wt2a[n * DD + k] = f2bf(W2a[i]);
    } else if (idx < 458752) {               // W2b: 512x256
        const int i = idx - 327680;
        const int k = i >> 8, n = i & 255;
        Wt2b[n * DD2 + k] = f2bf(W2b[i]);
    }
}

// ---------------------------------------------------------------------------
// CSR build: 256 threads, 2 threads per node, each scanning half the edges.
// Stable in edge order; stores LOCAL src ids per slot.
__global__ __launch_bounds__(256) void build_csr(const int* __restrict__ ei,
                                                 int* __restrict__ csr_src,
                                                 int* __restrict__ csr_start) {
    __shared__ int dstl[EPG];
    __shared__ int srcl[EPG];
    __shared__ int cnt2[2][NPG];
    __shared__ int sstart[NPG];
    const int b = blockIdx.x;
    const int t = threadIdx.x;
    const int* rowg = ei + b * EPG;
    const int* colg = ei + ETOT + b * EPG;
    for (int i = t; i < EPG; i += 256) {
        dstl[i] = colg[i] - b * NPG;
        srcl[i] = rowg[i] - b * NPG;
    }
    __syncthreads();
    const int node = t & 127;
    const int half = t >> 7;
    const int e0 = half * 256;
    int cnt = 0;
    for (int e = e0; e < e0 + 256; ++e) cnt += (dstl[e] == node);
    cnt2[half][node] = cnt;
    __syncthreads();
    if (half == 0) {
        int start = 0;
        for (int k = 0; k < node; ++k) start += cnt2[0][k] + cnt2[1][k];
        sstart[node] = start;
        csr_start[b * NPG + node] = b * EPG + start;
        if (b == 0 && node == 0) csr_start[NTOT] = ETOT;
    }
    __syncthreads();
    int kk = b * EPG + sstart[node] + (half ? cnt2[0][node] : 0);
    for (int e = e0; e < e0 + 256; ++e)
        if (dstl[e] == node) csr_src[kk++] = srcl[e];
}

// ---------------------------------------------------------------------------
// Layer-1 aggregate: s1 = bf16(x + agg(x)), per-graph LDS staged. x fp32 Nx128.
__global__ __launch_bounds__(256) void agg1(const float* __restrict__ x,
                                            const int* __restrict__ csr_src,
                                            const int* __restrict__ csr_start,
                                            ushortt* __restrict__ outp) {
    __shared__ float hx[NPG * DIN];     // 64 KB
    __shared__ int sstart[NPG + 1];
    __shared__ int ssrc[EPG];
    const int b = blockIdx.x;
    const int t = threadIdx.x;
    const float4* xg = (const float4*)(x + (size_t)b * NPG * DIN);
    float4* hx4 = (float4*)hx;
    for (int i = t; i < NPG * DIN / 4; i += 256) hx4[i] = xg[i];
    if (t < NPG + 1) sstart[t] = csr_start[b * NPG + t] - b * EPG;
    for (int i = t; i < EPG; i += 256) ssrc[i] = csr_src[b * EPG + i];
    __syncthreads();
    const int cg = t & 31;
    const int rsub = t >> 5;
    for (int row = rsub; row < NPG; row += 8) {
        float4 acc = *(const float4*)&hx[row * DIN + cg * 4];
        const int s = sstart[row], e = sstart[row + 1];
        for (int p = s; p < e; ++p) {
            const float4 nb = *(const float4*)&hx[ssrc[p] * DIN + cg * 4];
            acc.x += nb.x; acc.y += nb.y; acc.z += nb.z; acc.w += nb.w;
        }
        us4 o = { f2bf(acc.x), f2bf(acc.y), f2bf(acc.z), f2bf(acc.w) };
        *(us4*)&outp[(size_t)(b * NPG + row) * DIN + cg * 4] = o;
    }
}

// ---------------------------------------------------------------------------
// Layer-2 aggregate, fused with BN-apply+relu+vemb on staging.
__global__ __launch_bounds__(256) void agg2(const ushortt* __restrict__ h,
                                            const float* __restrict__ scale,
                                            const float* __restrict__ shift,
                                            const float* __restrict__ vemb,
                                            const int* __restrict__ csr_src,
                                            const int* __restrict__ csr_start,
                                            ushortt* __restrict__ outp) {
    __shared__ ushortt hp[NPG * DD];    // 64 KB
    __shared__ int sstart[NPG + 1];
    __shared__ int ssrc[EPG];
    const int b = blockIdx.x;
    const int t = threadIdx.x;
    const us4* zg = (const us4*)(h + (size_t)b * NPG * DD);
    us4* hp4 = (us4*)hp;
    for (int i = t; i < NPG * DD / 4; i += 256) {
        const us4 z4 = zg[i];
        const int c0 = (i & (DD / 4 - 1)) * 4;
        us4 o;
#pragma unroll
        for (int e = 0; e < 4; ++e) {
            float v = fmaf(bf2f(z4[e]), scale[c0 + e], shift[c0 + e]);
            v = fmaxf(v, 0.0f) + vemb[c0 + e];
            o[e] = f2bf(v);
        }
        hp4[i] = o;
    }
    if (t < NPG + 1) sstart[t] = csr_start[b * NPG + t] - b * EPG;
    for (int i = t; i < EPG; i += 256) ssrc[i] = csr_src[b * EPG + i];
    __syncthreads();
    const int cg = t & 63;
    const int rsub = t >> 6;
    for (int row = rsub; row < NPG; row += 4) {
        const us4 own = *(const us4*)&hp[row * DD + cg * 4];
        float4 acc = { bf2f(own.x), bf2f(own.y), bf2f(own.z), bf2f(own.w) };
        const int s = sstart[row], e = sstart[row + 1];
        for (int p = s; p < e; ++p) {
            const us4 nb = *(const us4*)&hp[ssrc[p] * DD + cg * 4];
            acc.x += bf2f(nb.x); acc.y += bf2f(nb.y);
            acc.z += bf2f(nb.z); acc.w += bf2f(nb.w);
        }
        us4 o = { f2bf(acc.x), f2bf(acc.y), f2bf(acc.z), f2bf(acc.w) };
        *(us4*)&outp[(size_t)(b * NPG + row) * DD + cg * 4] = o;
    }
}

// ---------------------------------------------------------------------------
// bf16 MFMA GEMM, 128x128 tile, BK=32, 4 waves. bf16 C = A@Wt^T + bias,
// fused fp64 BN partials, LDS-transposed coalesced C store.
#define BM 128
#define BN 128
#define BK 32
__global__ __launch_bounds__(256) void gemm_mfma(const ushortt* __restrict__ A,
                                                 const ushortt* __restrict__ Wt,
                                                 const float* __restrict__ bias,
                                                 ushortt* __restrict__ C,
                                                 double* __restrict__ psum,
                                                 double* __restrict__ psumsq,
                                                 int M, int N, int K) {
    __shared__ ushortt As[BM * BK];
    __shared__ ushortt Bs[BN * BK];
    __shared__ ushortt Cs[BM * BN];   // 32 KB
    __shared__ double redS[2][BN];
    __shared__ double redQ[2][BN];
    const int tid  = threadIdx.x;
    const int wave = tid >> 6;
    const int lane = tid & 63;
    const int qd = lane >> 4;
    const int r  = lane & 15;
    const int wm = (wave >> 1) * 64;
    const int wn = (wave & 1) * 64;
    const int m0 = blockIdx.y * BM;
    const int n0 = blockIdx.x * BN;

    f32x4 acc[4][4] = {};

    for (int k0 = 0; k0 < K; k0 += BK) {
#pragma unroll
        for (int s = 0; s < 2; ++s) {
            const int o   = wave * 128 + s * 64 + lane;
            const int row = o >> 2;
            const int cg  = o & 3;
            g2lds16(A  + (size_t)(m0 + row) * K + k0 + cg * 8,
                    &As[(size_t)(wave * 128 + s * 64) * 8]);
            g2lds16(Wt + (size_t)(n0 + row) * K + k0 + cg * 8,
                    &Bs[(size_t)(wave * 128 + s * 64) * 8]);
        }
        __syncthreads();
        short8 af[4], bfr[4];
#pragma unroll
        for (int i = 0; i < 4; ++i)
            af[i] = *(const short8*)&As[(wm + i * 16 + r) * BK + qd * 8];
#pragma unroll
        for (int j = 0; j < 4; ++j)
            bfr[j] = *(const short8*)&Bs[(wn + j * 16 + r) * BK + qd * 8];
#pragma unroll
        for (int i = 0; i < 4; ++i)
#pragma unroll
            for (int j = 0; j < 4; ++j)
                acc[i][j] = __builtin_amdgcn_mfma_f32_16x16x32_bf16(af[i], bfr[j], acc[i][j], 0, 0, 0);
        __syncthreads();
    }

    // Epilogue: bias, fp64 partials, C tile -> LDS (2B writes are cheap).
#pragma unroll
    for (int j = 0; j < 4; ++j) {
        const int coll = wn + j * 16 + r;
        const float bv = bias[n0 + coll];
        double s = 0.0, q = 0.0;
#pragma unroll
        for (int i = 0; i < 4; ++i) {
#pragma unroll
            for (int t = 0; t < 4; ++t) {
                const float v = acc[i][j][t] + bv;
                Cs[(wm + i * 16 + qd * 4 + t) * BN + coll] = f2bf(v);
                s += (double)v;
                q += (double)v * (double)v;
            }
        }
        s += __shfl_xor(s, 16); s += __shfl_xor(s, 32);
        q += __shfl_xor(q, 16); q += __shfl_xor(q, 32);
        if (qd == 0) {
            redS[wave >> 1][coll] = s;
            redQ[wave >> 1][coll] = q;
        }
    }
    __syncthreads();
    if (tid < BN) {
        psum[(size_t)blockIdx.y * N + n0 + tid]   = redS[0][tid] + redS[1][tid];
        psumsq[(size_t)blockIdx.y * N + n0 + tid] = redQ[0][tid] + redQ[1][tid];
    }
    // Coalesced C store: 16-B chunks, lanes cover rows contiguously.
#pragma unroll
    for (int s8 = 0; s8 < 8; ++s8) {
        const int c    = tid + 256 * s8;   // 0..2047
        const int row  = c >> 4;
        const int colc = (c & 15) * 8;
        const us8 v = *(const us8*)&Cs[row * BN + colc];
        *(us8*)&C[(size_t)(m0 + row) * N + n0 + colc] = v;
    }
}

// ---------------------------------------------------------------------------
__global__ __launch_bounds__(256) void bn_finalize(const double* __restrict__ psum,
                                                   const double* __restrict__ psumsq,
                                                   const float* __restrict__ g,
                                                   const float* __restrict__ be,
                                                   int ncols,
                                                   float* __restrict__ scale,
                                                   float* __restrict__ shift) {
    const int c = blockIdx.x * 256 + threadIdx.x;
    double s = 0.0, s2 = 0.0;
    for (int k = 0; k < NCHUNK; ++k) {
        s += psum[(size_t)k * ncols + c];
        s2 += psumsq[(size_t)k * ncols + c];
    }
    const double mean = s / (double)NTOT;
    const double var = s2 / (double)NTOT - mean * mean;
    const double rs = 1.0 / sqrt(var + 1e-5);
    const float sc = (float)((double)g[c] * rs);
    scale[c] = sc;
    shift[c] = (float)((double)be[c] - mean * (double)sc);
}

// out = bf16(relu(z*scale+shift)), us8 vectorized, bf16 in/out
__global__ __launch_bounds__(256) void bn_apply_vec(const ushortt* __restrict__ z,
                                                    const float* __restrict__ scale,
                                                    const float* __restrict__ shift,
                                                    ushortt* __restrict__ outp,
                                                    int ncolmask) {
    const size_t gi = (size_t)blockIdx.x * 256 + threadIdx.x;
    const size_t base = gi * 8;
    const int c0 = (int)(base & (size_t)ncolmask);
    const us8 z8 = *(const us8*)&z[base];
    us8 o;
#pragma unroll
    for (int e = 0; e < 8; ++e) {
        float v = fmaf(bf2f(z8[e]), scale[c0 + e], shift[c0 + e]);
        v = fmaxf(v, 0.0f);
        o[e] = f2bf(v);
    }
    *(us8*)&outp[base] = o;
}

// ---------------------------------------------------------------------------
// Fused tail: per-graph node dots (with BN folded in), edge scores, stable
// descending rank-sort, output gathers. One block per graph, 256 threads.
__global__ __launch_bounds__(256) void score_sort(const ushortt* __restrict__ h2,
                                                  const float* __restrict__ scale,
                                                  const float* __restrict__ shift,
                                                  const float* __restrict__ Wl,
                                                  const float* __restrict__ bl,
                                                  const int* __restrict__ ei,
                                                  float* __restrict__ out) {
    __shared__ float pa[NPG], pb[NPG];
    __shared__ float pw[EPG];
    __shared__ int ord[EPG];
    const int b = blockIdx.x;
    const int t = threadIdx.x;
    const int wave = t >> 6;
    const int lane = t & 63;
    // per-lane column slice (4 cols)
    const float4 w0 = *(const float4*)&Wl[lane * 4];
    const float4 w1 = *(const float4*)&Wl[DD + lane * 4];
    const float4 sc = *(const float4*)&scale[lane * 4];
    const float4 sh = *(const float4*)&shift[lane * 4];
    for (int n = wave; n < NPG; n += 4) {
        const us4 z4 = *(const us4*)&h2[(size_t)(b * NPG + n) * DD + lane * 4];
        const float x0 = fmaf(bf2f(z4.x), sc.x, sh.x);
        const float x1 = fmaf(bf2f(z4.y), sc.y, sh.y);
        const float x2 = fmaf(bf2f(z4.z), sc.z, sh.z);
        const float x3 = fmaf(bf2f(z4.w), sc.w, sh.w);
        float va = x0 * w0.x + x1 * w0.y + x2 * w0.z + x3 * w0.w;
        float vb = x0 * w1.x + x1 * w1.y + x2 * w1.z + x3 * w1.w;
#pragma unroll
        for (int off = 32; off >= 1; off >>= 1) {
            va += __shfl_down(va, off);
            vb += __shfl_down(vb, off);
        }
        if (lane == 0) { pa[n] = va; pb[n] = vb; }
    }
    __syncthreads();
    const float blv = bl[0];
    for (int e = t; e < EPG; e += 256) {
        const int rl = ei[b * EPG + e] - b * NPG;
        const int cl = ei[ETOT + b * EPG + e] - b * NPG;
        const float v = pa[rl] + pb[cl] + blv;
        pw[e] = v;
        out[OFF_PRED + b * EPG + e] = v;
    }
    __syncthreads();
    for (int e = t; e < EPG; e += 256) {
        const float v = pw[e];
        int rank = 0;
        for (int k = 0; k < EPG; ++k) {
            const float u = pw[k];
            rank += (u > v) || (u == v && k < e);
        }
        ord[rank] = e;
    }
    __syncthreads();
    for (int p = t; p < EPG; p += 256) {
        const int j = ord[p];
        const float wv = pw[j];
        const float e0 = (float)ei[b * EPG + j];
        const float e1 = (float)ei[ETOT + b * EPG + j];
        if (p < NRES) {
            out[OFF_CEI + b * NRES + p] = e0;
            out[OFF_CEI + BGR * NRES + b * NRES + p] = e1;
            out[OFF_CW + b * NRES + p] = wv;
        } else {
            const int pp = p - NRES;
            out[OFF_FEI + b * NRES + pp] = e0;
            out[OFF_FEI + BGR * NRES + b * NRES + pp] = e1;
            out[OFF_FW + b * NRES + pp] = -wv;
        }
    }
}

// ---------------------------------------------------------------------------
extern "C" void kernel_launch(void* const* d_in, const int* in_sizes, int n_in,
                              void* d_out, int out_size, void* d_ws, size_t ws_size,
                              hipStream_t stream) {
    (void)in_sizes; (void)n_in; (void)out_size; (void)ws_size;
    const float* x    = (const float*)d_in[0];
    const int*   ei   = (const int*)d_in[1];
    const float* vemb = (const float*)d_in[3];
    const float* W1a  = (const float*)d_in[4];
    const float* b1a  = (const float*)d_in[5];
    const float* g1a  = (const float*)d_in[6];
    const float* be1a = (const float*)d_in[7];
    const float* W1b  = (const float*)d_in[8];
    const float* b1b  = (const float*)d_in[9];
    const float* g1   = (const float*)d_in[10];
    const float* be1  = (const float*)d_in[11];
    const float* W2a  = (const float*)d_in[12];
    const float* b2a  = (const float*)d_in[13];
    const float* g2a  = (const float*)d_in[14];
    const float* be2a = (const float*)d_in[15];
    const float* W2b  = (const float*)d_in[16];
    const float* b2b  = (const float*)d_in[17];
    const float* g2   = (const float*)d_in[18];
    const float* be2  = (const float*)d_in[19];
    const float* Wl   = (const float*)d_in[20];
    const float* bl   = (const float*)d_in[21];
    float* out = (float*)d_out;

    char* wp = (char*)d_ws;
    auto alloc = [&](size_t bytes) -> char* {
        char* r = wp;
        wp += (bytes + 255) & ~(size_t)255;
        return r;
    };
    ushortt* zb    = (ushortt*)alloc((size_t)NTOT * 512 * 2);  // z1/h1/z2/h2
    ushortt* bufC  = (ushortt*)alloc((size_t)NTOT * 512 * 2);  // z1n / z2n
    ushortt* bufD  = (ushortt*)alloc((size_t)NTOT * 256 * 2);  // s2
    ushortt* bufS1 = (ushortt*)alloc((size_t)NTOT * 128 * 2);  // s1
    ushortt* Wt1a  = (ushortt*)alloc((size_t)DIN * DD2 * 2);
    ushortt* Wt1b  = (ushortt*)alloc((size_t)DD2 * DD * 2);
    ushortt* Wt2a  = (ushortt*)alloc((size_t)DD * DD2 * 2);
    ushortt* Wt2b  = (ushortt*)alloc((size_t)DD2 * DD * 2);
    double*  psum   = (double*)alloc((size_t)NCHUNK * 512 * 8);
    double*  psumsq = (double*)alloc((size_t)NCHUNK * 512 * 8);
    float*   scale  = (float*)alloc(512 * 4);
    float*   shift  = (float*)alloc(512 * 4);
    int*     csr_src   = (int*)alloc((size_t)ETOT * 4);
    int*     csr_start = (int*)alloc((size_t)(NTOT + 1) * 4);

    convert_all<<<1792, 256, 0, stream>>>(W1a, W1b, W2a, W2b, Wt1a, Wt1b, Wt2a, Wt2b);
    build_csr<<<BGR, 256, 0, stream>>>(ei, csr_src, csr_start);

    // 1) s1 = bf16(x + agg(x))
    agg1<<<BGR, 256, 0, stream>>>(x, csr_src, csr_start, bufS1);

    // 2) z1 = s1 @ W1a + b1a + fused stats
    gemm_mfma<<<dim3(DD2 / BN, NTOT / BM), 256, 0, stream>>>(bufS1, Wt1a, b1a, zb, psum, psumsq, NTOT, DD2, DIN);
    bn_finalize<<<2, 256, 0, stream>>>(psum, psumsq, g1a, be1a, DD2, scale, shift);
    bn_apply_vec<<<(NTOT * DD2) / 2048, 256, 0, stream>>>(zb, scale, shift, bufC, DD2 - 1);

    // 4) h1 = z1n @ W1b + b1b + fused stats
    gemm_mfma<<<dim3(DD / BN, NTOT / BM), 256, 0, stream>>>(bufC, Wt1b, b1b, zb, psum, psumsq, NTOT, DD, DD2);
    bn_finalize<<<1, 256, 0, stream>>>(psum, psumsq, g1, be1, DD, scale, shift);

    // 5+6) s2 = post + agg(post), post = relu(BN(h1)) + vemb fused in staging
    agg2<<<BGR, 256, 0, stream>>>(zb, scale, shift, vemb, csr_src, csr_start, bufD);

    // 7) z2 = s2 @ W2a + b2a + fused stats
    gemm_mfma<<<dim3(DD2 / BN, NTOT / BM), 256, 0, stream>>>(bufD, Wt2a, b2a, zb, psum, psumsq, NTOT, DD2, DD);
    bn_finalize<<<2, 256, 0, stream>>>(psum, psumsq, g2a, be2a, DD2, scale, shift);
    bn_apply_vec<<<(NTOT * DD2) / 2048, 256, 0, stream>>>(zb, scale, shift, bufC, DD2 - 1);

    // 9) h2 = z2n @ W2b + b2b + fused stats
    gemm_mfma<<<dim3(DD / BN, NTOT / BM), 256, 0, stream>>>(bufC, Wt2b, b2b, zb, psum, psumsq, NTOT, DD, DD2);
    bn_finalize<<<1, 256, 0, stream>>>(psum, psumsq, g2, be2, DD, scale, shift);

    // 10-12) fused: BN(h2) folded into dots, pred, stable sort, gathers
    score_sort<<<BGR, 256, 0, stream>>>(zb, scale, shift, Wl, bl, ei, out);
}

// Round 5
// 383.878 us; speedup vs baseline: 2.2492x; 1.1105x over previous
//
#include <hip/hip_runtime.h>

// Problem constants
#define BGR   256
#define NPG   128
#define EPG   512
#define DIN   128
#define DD    256
#define DD2   512
#define NTOT  (BGR * NPG)   // 32768
#define ETOT  (BGR * EPG)   // 131072
#define NRES  (EPG / 2)
#define NCHUNK 256          // M / BM row-chunks for BN partials

// Output layout (floats)
#define OFF_CEI  0
#define OFF_CW   (2 * BGR * NRES)
#define OFF_FEI  (OFF_CW + BGR * NRES)
#define OFF_FW   (OFF_FEI + 2 * BGR * NRES)
#define OFF_PRED (OFF_FW + BGR * NRES)

typedef unsigned short ushortt;
typedef __attribute__((ext_vector_type(4))) unsigned short us4;
typedef __attribute__((ext_vector_type(8))) unsigned short us8;
typedef __attribute__((ext_vector_type(8))) short short8;
typedef __attribute__((ext_vector_type(4))) float f32x4;

__device__ __forceinline__ ushortt f2bf(float f) {
    unsigned int u = __float_as_uint(f);
    unsigned int r = (u + 0x7fffu + ((u >> 16) & 1u)) >> 16;
    return (ushortt)r;
}
__device__ __forceinline__ float bf2f(ushortt u) {
    return __uint_as_float(((unsigned int)u) << 16);
}

__device__ __forceinline__ void g2lds16(const void* g, void* l) {
    __builtin_amdgcn_global_load_lds(
        (const __attribute__((address_space(1))) unsigned int*)g,
        (__attribute__((address_space(3))) unsigned int*)l, 16, 0, 0);
}

// ---------------------------------------------------------------------------
// All four weight transposes in one dispatch.
__global__ __launch_bounds__(256) void convert_all(const float* __restrict__ W1a,
                                                   const float* __restrict__ W1b,
                                                   const float* __restrict__ W2a,
                                                   const float* __restrict__ W2b,
                                                   ushortt* __restrict__ Wt1a,
                                                   ushortt* __restrict__ Wt1b,
                                                   ushortt* __restrict__ Wt2a,
                                                   ushortt* __restrict__ Wt2b) {
    const int idx = blockIdx.x * 256 + threadIdx.x;
    if (idx < 65536) {                       // W1a: 128x512
        const int k = idx >> 9, n = idx & 511;
        Wt1a[n * DIN + k] = f2bf(W1a[idx]);
    } else if (idx < 196608) {               // W1b: 512x256
        const int i = idx - 65536;
        const int k = i >> 8, n = i & 255;
        Wt1b[n * DD2 + k] = f2bf(W1b[i]);
    } else if (idx < 327680) {               // W2a: 256x512
        const int i = idx - 196608;
        const int k = i >> 9, n = i & 511;
        Wt2a[n * DD + k] = f2bf(W2a[i]);
    } else if (idx < 458752) {               // W2b: 512x256
        const int i = idx - 327680;
        const int k = i >> 8, n = i & 255;
        Wt2b[n * DD2 + k] = f2bf(W2b[i]);
    }
}

// ---------------------------------------------------------------------------
// Fused CSR build + layer-1 aggregate: builds the stable CSR (also written to
// global for agg2) and computes s1 = bf16(x + agg(x)) from the LDS-staged
// tile in one pass. One block per graph, 256 threads.
__global__ __launch_bounds__(256) void agg1_csr(const float* __restrict__ x,
                                                const int* __restrict__ ei,
                                                int* __restrict__ csr_src,
                                                int* __restrict__ csr_start,
                                                ushortt* __restrict__ outp) {
    __shared__ float hx[NPG * DIN];     // 64 KB
    __shared__ int dstl[EPG];
    __shared__ int srcl[EPG];
    __shared__ int ssrcs[EPG];          // csr-ordered local srcs
    __shared__ int cnt2[2][NPG];
    __shared__ int sstart[NPG + 1];
    const int b = blockIdx.x;
    const int t = threadIdx.x;
    // A: stage x tile + edge endpoints
    const float4* xg = (const float4*)(x + (size_t)b * NPG * DIN);
    float4* hx4 = (float4*)hx;
    for (int i = t; i < NPG * DIN / 4; i += 256) hx4[i] = xg[i];
    const int* rowg = ei + b * EPG;
    const int* colg = ei + ETOT + b * EPG;
    for (int i = t; i < EPG; i += 256) {
        dstl[i] = colg[i] - b * NPG;
        srcl[i] = rowg[i] - b * NPG;
    }
    __syncthreads();
    // B: per-node counts, split across two half-ranges (stable)
    const int node = t & 127;
    const int half = t >> 7;
    const int e0 = half * 256;
    int cnt = 0;
    for (int e = e0; e < e0 + 256; ++e) cnt += (dstl[e] == node);
    cnt2[half][node] = cnt;
    __syncthreads();
    // C: exclusive starts
    if (half == 0) {
        int start = 0;
        for (int k = 0; k < node; ++k) start += cnt2[0][k] + cnt2[1][k];
        sstart[node] = start;
        csr_start[b * NPG + node] = b * EPG + start;
        if (node == 0) sstart[NPG] = EPG;
        if (b == 0 && node == 0) csr_start[NTOT] = ETOT;
    }
    __syncthreads();
    // D: stable scatter (LDS + global copies)
    int kk = sstart[node] + (half ? cnt2[0][node] : 0);
    for (int e = e0; e < e0 + 256; ++e)
        if (dstl[e] == node) {
            ssrcs[kk] = srcl[e];
            csr_src[b * EPG + kk] = srcl[e];
            ++kk;
        }
    __syncthreads();
    // E: aggregate from LDS
    const int cg = t & 31;
    const int rsub = t >> 5;
    for (int row = rsub; row < NPG; row += 8) {
        float4 acc = *(const float4*)&hx[row * DIN + cg * 4];
        const int s = sstart[row], e = sstart[row + 1];
        for (int p = s; p < e; ++p) {
            const float4 nb = *(const float4*)&hx[ssrcs[p] * DIN + cg * 4];
            acc.x += nb.x; acc.y += nb.y; acc.z += nb.z; acc.w += nb.w;
        }
        us4 o = { f2bf(acc.x), f2bf(acc.y), f2bf(acc.z), f2bf(acc.w) };
        *(us4*)&outp[(size_t)(b * NPG + row) * DIN + cg * 4] = o;
    }
}

// ---------------------------------------------------------------------------
// Layer-2 aggregate, fused with BN-apply+relu+vemb on staging.
__global__ __launch_bounds__(256) void agg2(const ushortt* __restrict__ h,
                                            const float* __restrict__ scale,
                                            const float* __restrict__ shift,
                                            const float* __restrict__ vemb,
                                            const int* __restrict__ csr_src,
                                            const int* __restrict__ csr_start,
                                            ushortt* __restrict__ outp) {
    __shared__ ushortt hp[NPG * DD];    // 64 KB
    __shared__ int sstart[NPG + 1];
    __shared__ int ssrc[EPG];
    const int b = blockIdx.x;
    const int t = threadIdx.x;
    const us4* zg = (const us4*)(h + (size_t)b * NPG * DD);
    us4* hp4 = (us4*)hp;
    for (int i = t; i < NPG * DD / 4; i += 256) {
        const us4 z4 = zg[i];
        const int c0 = (i & (DD / 4 - 1)) * 4;
        us4 o;
#pragma unroll
        for (int e = 0; e < 4; ++e) {
            float v = fmaf(bf2f(z4[e]), scale[c0 + e], shift[c0 + e]);
            v = fmaxf(v, 0.0f) + vemb[c0 + e];
            o[e] = f2bf(v);
        }
        hp4[i] = o;
    }
    if (t < NPG + 1) sstart[t] = csr_start[b * NPG + t] - b * EPG;
    for (int i = t; i < EPG; i += 256) ssrc[i] = csr_src[b * EPG + i];
    __syncthreads();
    const int cg = t & 63;
    const int rsub = t >> 6;
    for (int row = rsub; row < NPG; row += 4) {
        const us4 own = *(const us4*)&hp[row * DD + cg * 4];
        float4 acc = { bf2f(own.x), bf2f(own.y), bf2f(own.z), bf2f(own.w) };
        const int s = sstart[row], e = sstart[row + 1];
        for (int p = s; p < e; ++p) {
            const us4 nb = *(const us4*)&hp[ssrc[p] * DD + cg * 4];
            acc.x += bf2f(nb.x); acc.y += bf2f(nb.y);
            acc.z += bf2f(nb.z); acc.w += bf2f(nb.w);
        }
        us4 o = { f2bf(acc.x), f2bf(acc.y), f2bf(acc.z), f2bf(acc.w) };
        *(us4*)&outp[(size_t)(b * NPG + row) * DD + cg * 4] = o;
    }
}

// ---------------------------------------------------------------------------
// bf16 MFMA GEMM, 128x128 tile, BK=32, 4 waves. bf16 C = A@Wt^T + bias,
// fused fp32 BN partials (chunk order fixed -> deterministic), LDS-transposed
// coalesced C store.
#define BM 128
#define BN 128
#define BK 32
__global__ __launch_bounds__(256) void gemm_mfma(const ushortt* __restrict__ A,
                                                 const ushortt* __restrict__ Wt,
                                                 const float* __restrict__ bias,
                                                 ushortt* __restrict__ C,
                                                 float* __restrict__ psum,
                                                 float* __restrict__ psumsq,
                                                 int M, int N, int K) {
    __shared__ ushortt As[BM * BK];
    __shared__ ushortt Bs[BN * BK];
    __shared__ ushortt Cs[BM * BN];   // 32 KB
    __shared__ float redS[2][BN];
    __shared__ float redQ[2][BN];
    const int tid  = threadIdx.x;
    const int wave = tid >> 6;
    const int lane = tid & 63;
    const int qd = lane >> 4;
    const int r  = lane & 15;
    const int wm = (wave >> 1) * 64;
    const int wn = (wave & 1) * 64;
    const int m0 = blockIdx.y * BM;
    const int n0 = blockIdx.x * BN;

    f32x4 acc[4][4] = {};

    for (int k0 = 0; k0 < K; k0 += BK) {
#pragma unroll
        for (int s = 0; s < 2; ++s) {
            const int o   = wave * 128 + s * 64 + lane;
            const int row = o >> 2;
            const int cg  = o & 3;
            g2lds16(A  + (size_t)(m0 + row) * K + k0 + cg * 8,
                    &As[(size_t)(wave * 128 + s * 64) * 8]);
            g2lds16(Wt + (size_t)(n0 + row) * K + k0 + cg * 8,
                    &Bs[(size_t)(wave * 128 + s * 64) * 8]);
        }
        __syncthreads();
        short8 af[4], bfr[4];
#pragma unroll
        for (int i = 0; i < 4; ++i)
            af[i] = *(const short8*)&As[(wm + i * 16 + r) * BK + qd * 8];
#pragma unroll
        for (int j = 0; j < 4; ++j)
            bfr[j] = *(const short8*)&Bs[(wn + j * 16 + r) * BK + qd * 8];
#pragma unroll
        for (int i = 0; i < 4; ++i)
#pragma unroll
            for (int j = 0; j < 4; ++j)
                acc[i][j] = __builtin_amdgcn_mfma_f32_16x16x32_bf16(af[i], bfr[j], acc[i][j], 0, 0, 0);
        __syncthreads();
    }

    // Epilogue: bias, fp32 partials, C tile -> LDS.
#pragma unroll
    for (int j = 0; j < 4; ++j) {
        const int coll = wn + j * 16 + r;
        const float bv = bias[n0 + coll];
        float s = 0.0f, q = 0.0f;
#pragma unroll
        for (int i = 0; i < 4; ++i) {
#pragma unroll
            for (int t = 0; t < 4; ++t) {
                const float v = acc[i][j][t] + bv;
                Cs[(wm + i * 16 + qd * 4 + t) * BN + coll] = f2bf(v);
                s += v;
                q = fmaf(v, v, q);
            }
        }
        s += __shfl_xor(s, 16); s += __shfl_xor(s, 32);
        q += __shfl_xor(q, 16); q += __shfl_xor(q, 32);
        if (qd == 0) {
            redS[wave >> 1][coll] = s;
            redQ[wave >> 1][coll] = q;
        }
    }
    __syncthreads();
    if (tid < BN) {
        psum[(size_t)blockIdx.y * N + n0 + tid]   = redS[0][tid] + redS[1][tid];
        psumsq[(size_t)blockIdx.y * N + n0 + tid] = redQ[0][tid] + redQ[1][tid];
    }
    // Coalesced C store: 16-B chunks, lanes cover rows contiguously.
#pragma unroll
    for (int s8 = 0; s8 < 8; ++s8) {
        const int c    = tid + 256 * s8;
        const int row  = c >> 4;
        const int colc = (c & 15) * 8;
        const us8 v = *(const us8*)&Cs[row * BN + colc];
        *(us8*)&C[(size_t)(m0 + row) * N + n0 + colc] = v;
    }
}

// ---------------------------------------------------------------------------
__global__ __launch_bounds__(256) void bn_finalize(const float* __restrict__ psum,
                                                   const float* __restrict__ psumsq,
                                                   const float* __restrict__ g,
                                                   const float* __restrict__ be,
                                                   int ncols,
                                                   float* __restrict__ scale,
                                                   float* __restrict__ shift) {
    const int c = blockIdx.x * 256 + threadIdx.x;
    double s = 0.0, s2 = 0.0;
    for (int k = 0; k < NCHUNK; ++k) {
        s += (double)psum[(size_t)k * ncols + c];
        s2 += (double)psumsq[(size_t)k * ncols + c];
    }
    const double mean = s / (double)NTOT;
    const double var = s2 / (double)NTOT - mean * mean;
    const double rs = 1.0 / sqrt(var + 1e-5);
    const float sc = (float)((double)g[c] * rs);
    scale[c] = sc;
    shift[c] = (float)((double)be[c] - mean * (double)sc);
}

// out = bf16(relu(z*scale+shift)), us8 vectorized, bf16 in/out
__global__ __launch_bounds__(256) void bn_apply_vec(const ushortt* __restrict__ z,
                                                    const float* __restrict__ scale,
                                                    const float* __restrict__ shift,
                                                    ushortt* __restrict__ outp,
                                                    int ncolmask) {
    const size_t gi = (size_t)blockIdx.x * 256 + threadIdx.x;
    const size_t base = gi * 8;
    const int c0 = (int)(base & (size_t)ncolmask);
    const us8 z8 = *(const us8*)&z[base];
    us8 o;
#pragma unroll
    for (int e = 0; e < 8; ++e) {
        float v = fmaf(bf2f(z8[e]), scale[c0 + e], shift[c0 + e]);
        v = fmaxf(v, 0.0f);
        o[e] = f2bf(v);
    }
    *(us8*)&outp[base] = o;
}

// ---------------------------------------------------------------------------
// Grid-wide per-node dots with BN folded: pa = (h2*sc+sh)·Wl[:256],
// pb = ·Wl[256:]. One wave per node, 8192 blocks -> TLP hides shfl latency.
__global__ __launch_bounds__(256) void node_dots_bn(const ushortt* __restrict__ h2,
                                                    const float* __restrict__ scale,
                                                    const float* __restrict__ shift,
                                                    const float* __restrict__ Wl,
                                                    float* __restrict__ pa,
                                                    float* __restrict__ pb) {
    const int wave = threadIdx.x >> 6;
    const int lane = threadIdx.x & 63;
    const int node = blockIdx.x * 4 + wave;
    const us4 z4 = *(const us4*)&h2[(size_t)node * DD + lane * 4];
    const float4 sc = *(const float4*)&scale[lane * 4];
    const float4 sh = *(const float4*)&shift[lane * 4];
    const float4 w0 = *(const float4*)&Wl[lane * 4];
    const float4 w1 = *(const float4*)&Wl[DD + lane * 4];
    const float x0 = fmaf(bf2f(z4.x), sc.x, sh.x);
    const float x1 = fmaf(bf2f(z4.y), sc.y, sh.y);
    const float x2 = fmaf(bf2f(z4.z), sc.z, sh.z);
    const float x3 = fmaf(bf2f(z4.w), sc.w, sh.w);
    float sa = x0 * w0.x + x1 * w0.y + x2 * w0.z + x3 * w0.w;
    float sb = x0 * w1.x + x1 * w1.y + x2 * w1.z + x3 * w1.w;
#pragma unroll
    for (int off = 32; off >= 1; off >>= 1) {
        sa += __shfl_down(sa, off);
        sb += __shfl_down(sb, off);
    }
    if (lane == 0) {
        pa[node] = sa;
        pb[node] = sb;
    }
}

// ---------------------------------------------------------------------------
// Per-graph: edge scores, stable descending rank-sort, output gathers.
// 512 threads (8 waves), 1 edge per thread.
__global__ __launch_bounds__(EPG) void sort_write(const float* __restrict__ pa,
                                                  const float* __restrict__ pb,
                                                  const float* __restrict__ bl,
                                                  const int* __restrict__ ei,
                                                  float* __restrict__ out) {
    __shared__ float pw[EPG];
    __shared__ int ord[EPG];
    const int b = blockIdx.x;
    const int t = threadIdx.x;
    const int rg = ei[b * EPG + t];
    const int cg = ei[ETOT + b * EPG + t];
    const float v = pa[rg] + pb[cg] + bl[0];
    pw[t] = v;
    out[OFF_PRED + b * EPG + t] = v;
    __syncthreads();
    int rank = 0;
#pragma unroll 8
    for (int k = 0; k < EPG; ++k) {
        const float u = pw[k];
        rank += (u > v) || (u == v && k < t);
    }
    ord[rank] = t;
    __syncthreads();
    const int j = ord[t];
    const float wv = pw[j];
    const float e0 = (float)ei[b * EPG + j];
    const float e1 = (float)ei[ETOT + b * EPG + j];
    if (t < NRES) {
        out[OFF_CEI + b * NRES + t] = e0;
        out[OFF_CEI + BGR * NRES + b * NRES + t] = e1;
        out[OFF_CW + b * NRES + t] = wv;
    } else {
        const int p = t - NRES;
        out[OFF_FEI + b * NRES + p] = e0;
        out[OFF_FEI + BGR * NRES + b * NRES + p] = e1;
        out[OFF_FW + b * NRES + p] = -wv;
    }
}

// ---------------------------------------------------------------------------
extern "C" void kernel_launch(void* const* d_in, const int* in_sizes, int n_in,
                              void* d_out, int out_size, void* d_ws, size_t ws_size,
                              hipStream_t stream) {
    (void)in_sizes; (void)n_in; (void)out_size; (void)ws_size;
    const float* x    = (const float*)d_in[0];
    const int*   ei   = (const int*)d_in[1];
    const float* vemb = (const float*)d_in[3];
    const float* W1a  = (const float*)d_in[4];
    const float* b1a  = (const float*)d_in[5];
    const float* g1a  = (const float*)d_in[6];
    const float* be1a = (const float*)d_in[7];
    const float* W1b  = (const float*)d_in[8];
    const float* b1b  = (const float*)d_in[9];
    const float* g1   = (const float*)d_in[10];
    const float* be1  = (const float*)d_in[11];
    const float* W2a  = (const float*)d_in[12];
    const float* b2a  = (const float*)d_in[13];
    const float* g2a  = (const float*)d_in[14];
    const float* be2a = (const float*)d_in[15];
    const float* W2b  = (const float*)d_in[16];
    const float* b2b  = (const float*)d_in[17];
    const float* g2   = (const float*)d_in[18];
    const float* be2  = (const float*)d_in[19];
    const float* Wl   = (const float*)d_in[20];
    const float* bl   = (const float*)d_in[21];
    float* out = (float*)d_out;

    char* wp = (char*)d_ws;
    auto alloc = [&](size_t bytes) -> char* {
        char* r = wp;
        wp += (bytes + 255) & ~(size_t)255;
        return r;
    };
    ushortt* zb    = (ushortt*)alloc((size_t)NTOT * 512 * 2);  // z1/h1/z2/h2
    ushortt* bufC  = (ushortt*)alloc((size_t)NTOT * 512 * 2);  // z1n / z2n
    ushortt* bufD  = (ushortt*)alloc((size_t)NTOT * 256 * 2);  // s2
    ushortt* bufS1 = (ushortt*)alloc((size_t)NTOT * 128 * 2);  // s1
    ushortt* Wt1a  = (ushortt*)alloc((size_t)DIN * DD2 * 2);
    ushortt* Wt1b  = (ushortt*)alloc((size_t)DD2 * DD * 2);
    ushortt* Wt2a  = (ushortt*)alloc((size_t)DD * DD2 * 2);
    ushortt* Wt2b  = (ushortt*)alloc((size_t)DD2 * DD * 2);
    float*   psum   = (float*)alloc((size_t)NCHUNK * 512 * 4);
    float*   psumsq = (float*)alloc((size_t)NCHUNK * 512 * 4);
    float*   scale  = (float*)alloc(512 * 4);
    float*   shift  = (float*)alloc(512 * 4);
    float*   pa     = (float*)alloc((size_t)NTOT * 4);
    float*   pb     = (float*)alloc((size_t)NTOT * 4);
    int*     csr_src   = (int*)alloc((size_t)ETOT * 4);
    int*     csr_start = (int*)alloc((size_t)(NTOT + 1) * 4);

    convert_all<<<1792, 256, 0, stream>>>(W1a, W1b, W2a, W2b, Wt1a, Wt1b, Wt2a, Wt2b);

    // 0+1) fused CSR build + s1 = bf16(x + agg(x))
    agg1_csr<<<BGR, 256, 0, stream>>>(x, ei, csr_src, csr_start, bufS1);

    // 2) z1 = s1 @ W1a + b1a + fused stats
    gemm_mfma<<<dim3(DD2 / BN, NTOT / BM), 256, 0, stream>>>(bufS1, Wt1a, b1a, zb, psum, psumsq, NTOT, DD2, DIN);
    bn_finalize<<<2, 256, 0, stream>>>(psum, psumsq, g1a, be1a, DD2, scale, shift);
    bn_apply_vec<<<(NTOT * DD2) / 2048, 256, 0, stream>>>(zb, scale, shift, bufC, DD2 - 1);

    // 4) h1 = z1n @ W1b + b1b + fused stats
    gemm_mfma<<<dim3(DD / BN, NTOT / BM), 256, 0, stream>>>(bufC, Wt1b, b1b, zb, psum, psumsq, NTOT, DD, DD2);
    bn_finalize<<<1, 256, 0, stream>>>(psum, psumsq, g1, be1, DD, scale, shift);

    // 5+6) s2 = post + agg(post), post = relu(BN(h1)) + vemb fused in staging
    agg2<<<BGR, 256, 0, stream>>>(zb, scale, shift, vemb, csr_src, csr_start, bufD);

    // 7) z2 = s2 @ W2a + b2a + fused stats
    gemm_mfma<<<dim3(DD2 / BN, NTOT / BM), 256, 0, stream>>>(bufD, Wt2a, b2a, zb, psum, psumsq, NTOT, DD2, DD);
    bn_finalize<<<2, 256, 0, stream>>>(psum, psumsq, g2a, be2a, DD2, scale, shift);
    bn_apply_vec<<<(NTOT * DD2) / 2048, 256, 0, stream>>>(zb, scale, shift, bufC, DD2 - 1);

    // 9) h2 = z2n @ W2b + b2b + fused stats
    gemm_mfma<<<dim3(DD / BN, NTOT / BM), 256, 0, stream>>>(bufC, Wt2b, b2b, zb, psum, psumsq, NTOT, DD, DD2);
    bn_finalize<<<1, 256, 0, stream>>>(psum, psumsq, g2, be2, DD, scale, shift);

    // 10) pa/pb with BN folded (grid-wide TLP)
    node_dots_bn<<<NTOT / 4, 256, 0, stream>>>(zb, scale, shift, Wl, pa, pb);

    // 11-12) per-graph scores + stable sort + gathers (512 thr)
    sort_write<<<BGR, EPG, 0, stream>>>(pa, pb, bl, ei, out);
}

// Round 6
// 344.693 us; speedup vs baseline: 2.5049x; 1.1137x over previous
//
#include <hip/hip_runtime.h>

// Problem constants
#define BGR   256
#define NPG   128
#define EPG   512
#define DIN   128
#define DD    256
#define DD2   512
#define NTOT  (BGR * NPG)   // 32768
#define ETOT  (BGR * EPG)   // 131072
#define NRES  (EPG / 2)
#define NCHUNK 256          // M / BM row-chunks for BN partials
#define MP    136           // padded LDS stride (elements): 272B, 16B-aligned, 2-way banks

// Output layout (floats)
#define OFF_CEI  0
#define OFF_CW   (2 * BGR * NRES)
#define OFF_FEI  (OFF_CW + BGR * NRES)
#define OFF_FW   (OFF_FEI + 2 * BGR * NRES)
#define OFF_PRED (OFF_FW + BGR * NRES)

typedef unsigned short ushortt;
typedef __attribute__((ext_vector_type(4))) unsigned short us4;
typedef __attribute__((ext_vector_type(8))) unsigned short us8;
typedef __attribute__((ext_vector_type(8))) short short8;
typedef __attribute__((ext_vector_type(4))) float f32x4;

__device__ __forceinline__ ushortt f2bf(float f) {
    unsigned int u = __float_as_uint(f);
    unsigned int r = (u + 0x7fffu + ((u >> 16) & 1u)) >> 16;
    return (ushortt)r;
}
__device__ __forceinline__ float bf2f(ushortt u) {
    return __uint_as_float(((unsigned int)u) << 16);
}

__device__ __forceinline__ void g2lds16(const void* g, void* l) {
    __builtin_amdgcn_global_load_lds(
        (const __attribute__((address_space(1))) unsigned int*)g,
        (__attribute__((address_space(3))) unsigned int*)l, 16, 0, 0);
}

// ---------------------------------------------------------------------------
// All four weight transposes in one dispatch.
__global__ __launch_bounds__(256) void convert_all(const float* __restrict__ W1a,
                                                   const float* __restrict__ W1b,
                                                   const float* __restrict__ W2a,
                                                   const float* __restrict__ W2b,
                                                   ushortt* __restrict__ Wt1a,
                                                   ushortt* __restrict__ Wt1b,
                                                   ushortt* __restrict__ Wt2a,
                                                   ushortt* __restrict__ Wt2b) {
    const int idx = blockIdx.x * 256 + threadIdx.x;
    if (idx < 65536) {                       // W1a: 128x512
        const int k = idx >> 9, n = idx & 511;
        Wt1a[n * DIN + k] = f2bf(W1a[idx]);
    } else if (idx < 196608) {               // W1b: 512x256
        const int i = idx - 65536;
        const int k = i >> 8, n = i & 255;
        Wt1b[n * DD2 + k] = f2bf(W1b[i]);
    } else if (idx < 327680) {               // W2a: 256x512
        const int i = idx - 196608;
        const int k = i >> 9, n = i & 511;
        Wt2a[n * DD + k] = f2bf(W2a[i]);
    } else if (idx < 458752) {               // W2b: 512x256
        const int i = idx - 327680;
        const int k = i >> 8, n = i & 255;
        Wt2b[n * DD2 + k] = f2bf(W2b[i]);
    }
}

// ---------------------------------------------------------------------------
// Per-graph multiplicity matrix M = I + A^T (bf16, exact small ints).
// M[dst][src] = #edges(src->dst) + (dst==src).
__global__ __launch_bounds__(256) void build_adj(const int* __restrict__ ei,
                                                 ushortt* __restrict__ Madj) {
    __shared__ int cnt[NPG * NPG];   // 64 KB
    const int b = blockIdx.x, t = threadIdx.x;
    for (int i = t; i < NPG * NPG; i += 256) cnt[i] = 0;
    __syncthreads();
    for (int e = t; e < EPG; e += 256) {
        const int src = ei[b * EPG + e] - b * NPG;
        const int dst = ei[ETOT + b * EPG + e] - b * NPG;
        atomicAdd(&cnt[dst * NPG + src], 1);
    }
    __syncthreads();
#pragma unroll
    for (int k = 0; k < 8; ++k) {
        const int i0 = (t + k * 256) * 8;
        us8 o;
#pragma unroll
        for (int e = 0; e < 8; ++e) {
            const int i = i0 + e;
            const int v = cnt[i] + (((i >> 7) == (i & 127)) ? 1 : 0);
            o[e] = f2bf((float)v);
        }
        *(us8*)&Madj[(size_t)b * NPG * NPG + i0] = o;
    }
}

// ---------------------------------------------------------------------------
// Layer-1 aggregate as MFMA: s1 = bf16( M @ bf16(x) ).  One block per graph.
__global__ __launch_bounds__(256) void agg1_mm(const float* __restrict__ x,
                                               const ushortt* __restrict__ Madj,
                                               ushortt* __restrict__ s1) {
    __shared__ ushortt Ms[NPG * MP];    // 34 KB [m][s] padded
    __shared__ ushortt XT[DIN * MP];    // 34 KB [c][s] padded (B-operand layout)
    const int b = blockIdx.x, t = threadIdx.x;
    const int wave = t >> 6, lane = t & 63;
    const int qd = lane >> 4, r = lane & 15;
    // stage M (padded rows, 16B chunks)
    const ushortt* Mg = Madj + (size_t)b * NPG * NPG;
#pragma unroll
    for (int k = 0; k < 8; ++k) {
        const int ch = t + k * 256;
        const int m = ch >> 4, sc = (ch & 15) * 8;
        *(us8*)&Ms[m * MP + sc] = *(const us8*)&Mg[m * NPG + sc];
    }
    // x -> XT (transpose + bf16); rows coalesced, 2B LDS scatter
#pragma unroll 4
    for (int it = 0; it < 64; ++it) {
        const int s = it * 2 + (t >> 7);
        const int c = t & 127;
        XT[c * MP + s] = f2bf(x[(size_t)(b * NPG + s) * DIN + c]);
    }
    __syncthreads();
    const int wm = (wave >> 1) * 64, wn = (wave & 1) * 64;
    f32x4 acc[4][4] = {};
#pragma unroll
    for (int ks = 0; ks < 4; ++ks) {
        const int k0 = ks * 32 + qd * 8;
        short8 af[4], bfr[4];
#pragma unroll
        for (int i = 0; i < 4; ++i)
            af[i] = *(const short8*)&Ms[(wm + i * 16 + r) * MP + k0];
#pragma unroll
        for (int j = 0; j < 4; ++j)
            bfr[j] = *(const short8*)&XT[(wn + j * 16 + r) * MP + k0];
#pragma unroll
        for (int i = 0; i < 4; ++i)
#pragma unroll
            for (int j = 0; j < 4; ++j)
                acc[i][j] = __builtin_amdgcn_mfma_f32_16x16x32_bf16(af[i], bfr[j], acc[i][j], 0, 0, 0);
    }
    __syncthreads();
    ushortt* Cs = Ms;   // reuse, stride DIN
#pragma unroll
    for (int j = 0; j < 4; ++j) {
        const int coll = wn + j * 16 + r;
#pragma unroll
        for (int i = 0; i < 4; ++i)
#pragma unroll
            for (int tt = 0; tt < 4; ++tt)
                Cs[(wm + i * 16 + qd * 4 + tt) * DIN + coll] = f2bf(acc[i][j][tt]);
    }
    __syncthreads();
#pragma unroll
    for (int k = 0; k < 8; ++k) {
        const int ch = t + k * 256;
        const int row = ch >> 4, colc = (ch & 15) * 8;
        *(us8*)&s1[(size_t)(b * NPG + row) * DIN + colc] = *(const us8*)&Cs[row * DIN + colc];
    }
}

// ---------------------------------------------------------------------------
// Layer-2 aggregate as MFMA, BN+relu+vemb fused into the transpose staging:
// post = bf16(relu(h*scale+shift)+vemb);  s2 = bf16(M @ post).
// Grid (2 n-halves, BGR graphs); each block computes 128 rows x 128 cols.
__global__ __launch_bounds__(256) void agg2_mm(const ushortt* __restrict__ h,
                                               const float* __restrict__ scale,
                                               const float* __restrict__ shift,
                                               const float* __restrict__ vemb,
                                               const ushortt* __restrict__ Madj,
                                               ushortt* __restrict__ s2) {
    __shared__ ushortt Ms[NPG * MP];
    __shared__ ushortt PT[NPG * MP];    // local col block [cl][s]
    const int nb = blockIdx.x, b = blockIdx.y, t = threadIdx.x;
    const int wave = t >> 6, lane = t & 63;
    const int qd = lane >> 4, r = lane & 15;
    const ushortt* Mg = Madj + (size_t)b * NPG * NPG;
#pragma unroll
    for (int k = 0; k < 8; ++k) {
        const int ch = t + k * 256;
        const int m = ch >> 4, sc = (ch & 15) * 8;
        *(us8*)&Ms[m * MP + sc] = *(const us8*)&Mg[m * NPG + sc];
    }
    const int cl = t & 127;
    const int c = nb * 128 + cl;
    const float scv = scale[c], shv = shift[c], vev = vemb[c];
#pragma unroll 4
    for (int it = 0; it < 64; ++it) {
        const int s = it * 2 + (t >> 7);
        float v = fmaf(bf2f(h[(size_t)(b * NPG + s) * DD + c]), scv, shv);
        PT[cl * MP + s] = f2bf(fmaxf(v, 0.0f) + vev);
    }
    __syncthreads();
    const int wm = (wave >> 1) * 64, wn = (wave & 1) * 64;
    f32x4 acc[4][4] = {};
#pragma unroll
    for (int ks = 0; ks < 4; ++ks) {
        const int k0 = ks * 32 + qd * 8;
        short8 af[4], bfr[4];
#pragma unroll
        for (int i = 0; i < 4; ++i)
            af[i] = *(const short8*)&Ms[(wm + i * 16 + r) * MP + k0];
#pragma unroll
        for (int j = 0; j < 4; ++j)
            bfr[j] = *(const short8*)&PT[(wn + j * 16 + r) * MP + k0];
#pragma unroll
        for (int i = 0; i < 4; ++i)
#pragma unroll
            for (int j = 0; j < 4; ++j)
                acc[i][j] = __builtin_amdgcn_mfma_f32_16x16x32_bf16(af[i], bfr[j], acc[i][j], 0, 0, 0);
    }
    __syncthreads();
    ushortt* Cs = Ms;   // reuse, stride 128
#pragma unroll
    for (int j = 0; j < 4; ++j) {
        const int coll = wn + j * 16 + r;
#pragma unroll
        for (int i = 0; i < 4; ++i)
#pragma unroll
            for (int tt = 0; tt < 4; ++tt)
                Cs[(wm + i * 16 + qd * 4 + tt) * 128 + coll] = f2bf(acc[i][j][tt]);
    }
    __syncthreads();
#pragma unroll
    for (int k = 0; k < 8; ++k) {
        const int ch = t + k * 256;
        const int row = ch >> 4, colc = (ch & 15) * 8;
        *(us8*)&s2[(size_t)(b * NPG + row) * DD + nb * 128 + colc] =
            *(const us8*)&Cs[row * 128 + colc];
    }
}

// ---------------------------------------------------------------------------
// bf16 MFMA GEMM, 128x128 tile, BK=32, 4 waves. bf16 C = A@Wt^T + bias,
// fused fp32 BN partials, LDS-transposed coalesced C store.
#define BM 128
#define BN 128
#define BK 32
__global__ __launch_bounds__(256) void gemm_mfma(const ushortt* __restrict__ A,
                                                 const ushortt* __restrict__ Wt,
                                                 const float* __restrict__ bias,
                                                 ushortt* __restrict__ C,
                                                 float* __restrict__ psum,
                                                 float* __restrict__ psumsq,
                                                 int M, int N, int K) {
    __shared__ ushortt As[BM * BK];
    __shared__ ushortt Bs[BN * BK];
    __shared__ ushortt Cs[BM * BN];   // 32 KB
    __shared__ float redS[2][BN];
    __shared__ float redQ[2][BN];
    const int tid  = threadIdx.x;
    const int wave = tid >> 6;
    const int lane = tid & 63;
    const int qd = lane >> 4;
    const int r  = lane & 15;
    const int wm = (wave >> 1) * 64;
    const int wn = (wave & 1) * 64;
    const int m0 = blockIdx.y * BM;
    const int n0 = blockIdx.x * BN;

    f32x4 acc[4][4] = {};

    for (int k0 = 0; k0 < K; k0 += BK) {
#pragma unroll
        for (int s = 0; s < 2; ++s) {
            const int o   = wave * 128 + s * 64 + lane;
            const int row = o >> 2;
            const int cg  = o & 3;
            g2lds16(A  + (size_t)(m0 + row) * K + k0 + cg * 8,
                    &As[(size_t)(wave * 128 + s * 64) * 8]);
            g2lds16(Wt + (size_t)(n0 + row) * K + k0 + cg * 8,
                    &Bs[(size_t)(wave * 128 + s * 64) * 8]);
        }
        __syncthreads();
        short8 af[4], bfr[4];
#pragma unroll
        for (int i = 0; i < 4; ++i)
            af[i] = *(const short8*)&As[(wm + i * 16 + r) * BK + qd * 8];
#pragma unroll
        for (int j = 0; j < 4; ++j)
            bfr[j] = *(const short8*)&Bs[(wn + j * 16 + r) * BK + qd * 8];
#pragma unroll
        for (int i = 0; i < 4; ++i)
#pragma unroll
            for (int j = 0; j < 4; ++j)
                acc[i][j] = __builtin_amdgcn_mfma_f32_16x16x32_bf16(af[i], bfr[j], acc[i][j], 0, 0, 0);
        __syncthreads();
    }

#pragma unroll
    for (int j = 0; j < 4; ++j) {
        const int coll = wn + j * 16 + r;
        const float bv = bias[n0 + coll];
        float s = 0.0f, q = 0.0f;
#pragma unroll
        for (int i = 0; i < 4; ++i) {
#pragma unroll
            for (int t = 0; t < 4; ++t) {
                const float v = acc[i][j][t] + bv;
                Cs[(wm + i * 16 + qd * 4 + t) * BN + coll] = f2bf(v);
                s += v;
                q = fmaf(v, v, q);
            }
        }
        s += __shfl_xor(s, 16); s += __shfl_xor(s, 32);
        q += __shfl_xor(q, 16); q += __shfl_xor(q, 32);
        if (qd == 0) {
            redS[wave >> 1][coll] = s;
            redQ[wave >> 1][coll] = q;
        }
    }
    __syncthreads();
    if (tid < BN) {
        psum[(size_t)blockIdx.y * N + n0 + tid]   = redS[0][tid] + redS[1][tid];
        psumsq[(size_t)blockIdx.y * N + n0 + tid] = redQ[0][tid] + redQ[1][tid];
    }
#pragma unroll
    for (int s8 = 0; s8 < 8; ++s8) {
        const int c    = tid + 256 * s8;
        const int row  = c >> 4;
        const int colc = (c & 15) * 8;
        const us8 v = *(const us8*)&Cs[row * BN + colc];
        *(us8*)&C[(size_t)(m0 + row) * N + n0 + colc] = v;
    }
}

// ---------------------------------------------------------------------------
__global__ __launch_bounds__(256) void bn_finalize(const float* __restrict__ psum,
                                                   const float* __restrict__ psumsq,
                                                   const float* __restrict__ g,
                                                   const float* __restrict__ be,
                                                   int ncols,
                                                   float* __restrict__ scale,
                                                   float* __restrict__ shift) {
    const int c = blockIdx.x * 256 + threadIdx.x;
    double s = 0.0, s2 = 0.0;
    for (int k = 0; k < NCHUNK; ++k) {
        s += (double)psum[(size_t)k * ncols + c];
        s2 += (double)psumsq[(size_t)k * ncols + c];
    }
    const double mean = s / (double)NTOT;
    const double var = s2 / (double)NTOT - mean * mean;
    const double rs = 1.0 / sqrt(var + 1e-5);
    const float sc = (float)((double)g[c] * rs);
    scale[c] = sc;
    shift[c] = (float)((double)be[c] - mean * (double)sc);
}

// out = bf16(relu(z*scale+shift)), us8 vectorized, bf16 in/out
__global__ __launch_bounds__(256) void bn_apply_vec(const ushortt* __restrict__ z,
                                                    const float* __restrict__ scale,
                                                    const float* __restrict__ shift,
                                                    ushortt* __restrict__ outp,
                                                    int ncolmask) {
    const size_t gi = (size_t)blockIdx.x * 256 + threadIdx.x;
    const size_t base = gi * 8;
    const int c0 = (int)(base & (size_t)ncolmask);
    const us8 z8 = *(const us8*)&z[base];
    us8 o;
#pragma unroll
    for (int e = 0; e < 8; ++e) {
        float v = fmaf(bf2f(z8[e]), scale[c0 + e], shift[c0 + e]);
        v = fmaxf(v, 0.0f);
        o[e] = f2bf(v);
    }
    *(us8*)&outp[base] = o;
}

// ---------------------------------------------------------------------------
// Grid-wide per-node dots with BN folded.
__global__ __launch_bounds__(256) void node_dots_bn(const ushortt* __restrict__ h2,
                                                    const float* __restrict__ scale,
                                                    const float* __restrict__ shift,
                                                    const float* __restrict__ Wl,
                                                    float* __restrict__ pa,
                                                    float* __restrict__ pb) {
    const int wave = threadIdx.x >> 6;
    const int lane = threadIdx.x & 63;
    const int node = blockIdx.x * 4 + wave;
    const us4 z4 = *(const us4*)&h2[(size_t)node * DD + lane * 4];
    const float4 sc = *(const float4*)&scale[lane * 4];
    const float4 sh = *(const float4*)&shift[lane * 4];
    const float4 w0 = *(const float4*)&Wl[lane * 4];
    const float4 w1 = *(const float4*)&Wl[DD + lane * 4];
    const float x0 = fmaf(bf2f(z4.x), sc.x, sh.x);
    const float x1 = fmaf(bf2f(z4.y), sc.y, sh.y);
    const float x2 = fmaf(bf2f(z4.z), sc.z, sh.z);
    const float x3 = fmaf(bf2f(z4.w), sc.w, sh.w);
    float sa = x0 * w0.x + x1 * w0.y + x2 * w0.z + x3 * w0.w;
    float sb = x0 * w1.x + x1 * w1.y + x2 * w1.z + x3 * w1.w;
#pragma unroll
    for (int off = 32; off >= 1; off >>= 1) {
        sa += __shfl_down(sa, off);
        sb += __shfl_down(sb, off);
    }
    if (lane == 0) {
        pa[node] = sa;
        pb[node] = sb;
    }
}

// ---------------------------------------------------------------------------
// Per-graph: edge scores, stable descending rank-sort, output gathers.
__global__ __launch_bounds__(EPG) void sort_write(const float* __restrict__ pa,
                                                  const float* __restrict__ pb,
                                                  const float* __restrict__ bl,
                                                  const int* __restrict__ ei,
                                                  float* __restrict__ out) {
    __shared__ float pw[EPG];
    __shared__ int ord[EPG];
    const int b = blockIdx.x;
    const int t = threadIdx.x;
    const int rg = ei[b * EPG + t];
    const int cg = ei[ETOT + b * EPG + t];
    const float v = pa[rg] + pb[cg] + bl[0];
    pw[t] = v;
    out[OFF_PRED + b * EPG + t] = v;
    __syncthreads();
    int rank = 0;
#pragma unroll 8
    for (int k = 0; k < EPG; ++k) {
        const float u = pw[k];
        rank += (u > v) || (u == v && k < t);
    }
    ord[rank] = t;
    __syncthreads();
    const int j = ord[t];
    const float wv = pw[j];
    const float e0 = (float)ei[b * EPG + j];
    const float e1 = (float)ei[ETOT + b * EPG + j];
    if (t < NRES) {
        out[OFF_CEI + b * NRES + t] = e0;
        out[OFF_CEI + BGR * NRES + b * NRES + t] = e1;
        out[OFF_CW + b * NRES + t] = wv;
    } else {
        const int p = t - NRES;
        out[OFF_FEI + b * NRES + p] = e0;
        out[OFF_FEI + BGR * NRES + b * NRES + p] = e1;
        out[OFF_FW + b * NRES + p] = -wv;
    }
}

// ---------------------------------------------------------------------------
extern "C" void kernel_launch(void* const* d_in, const int* in_sizes, int n_in,
                              void* d_out, int out_size, void* d_ws, size_t ws_size,
                              hipStream_t stream) {
    (void)in_sizes; (void)n_in; (void)out_size; (void)ws_size;
    const float* x    = (const float*)d_in[0];
    const int*   ei   = (const int*)d_in[1];
    const float* vemb = (const float*)d_in[3];
    const float* W1a  = (const float*)d_in[4];
    const float* b1a  = (const float*)d_in[5];
    const float* g1a  = (const float*)d_in[6];
    const float* be1a = (const float*)d_in[7];
    const float* W1b  = (const float*)d_in[8];
    const float* b1b  = (const float*)d_in[9];
    const float* g1   = (const float*)d_in[10];
    const float* be1  = (const float*)d_in[11];
    const float* W2a  = (const float*)d_in[12];
    const float* b2a  = (const float*)d_in[13];
    const float* g2a  = (const float*)d_in[14];
    const float* be2a = (const float*)d_in[15];
    const float* W2b  = (const float*)d_in[16];
    const float* b2b  = (const float*)d_in[17];
    const float* g2   = (const float*)d_in[18];
    const float* be2  = (const float*)d_in[19];
    const float* Wl   = (const float*)d_in[20];
    const float* bl   = (const float*)d_in[21];
    float* out = (float*)d_out;

    char* wp = (char*)d_ws;
    auto alloc = [&](size_t bytes) -> char* {
        char* r = wp;
        wp += (bytes + 255) & ~(size_t)255;
        return r;
    };
    ushortt* zb    = (ushortt*)alloc((size_t)NTOT * 512 * 2);  // z1/h1/z2/h2
    ushortt* bufC  = (ushortt*)alloc((size_t)NTOT * 512 * 2);  // z1n / z2n
    ushortt* bufD  = (ushortt*)alloc((size_t)NTOT * 256 * 2);  // s2
    ushortt* bufS1 = (ushortt*)alloc((size_t)NTOT * 128 * 2);  // s1
    ushortt* Madj  = (ushortt*)alloc((size_t)BGR * NPG * NPG * 2);  // 8 MB
    ushortt* Wt1a  = (ushortt*)alloc((size_t)DIN * DD2 * 2);
    ushortt* Wt1b  = (ushortt*)alloc((size_t)DD2 * DD * 2);
    ushortt* Wt2a  = (ushortt*)alloc((size_t)DD * DD2 * 2);
    ushortt* Wt2b  = (ushortt*)alloc((size_t)DD2 * DD * 2);
    float*   psum   = (float*)alloc((size_t)NCHUNK * 512 * 4);
    float*   psumsq = (float*)alloc((size_t)NCHUNK * 512 * 4);
    float*   scale  = (float*)alloc(512 * 4);
    float*   shift  = (float*)alloc(512 * 4);
    float*   pa     = (float*)alloc((size_t)NTOT * 4);
    float*   pb     = (float*)alloc((size_t)NTOT * 4);

    convert_all<<<1792, 256, 0, stream>>>(W1a, W1b, W2a, W2b, Wt1a, Wt1b, Wt2a, Wt2b);

    // 0) adjacency multiplicity matrices (I + A^T), bf16
    build_adj<<<BGR, 256, 0, stream>>>(ei, Madj);

    // 1) s1 = bf16(M @ bf16(x))
    agg1_mm<<<BGR, 256, 0, stream>>>(x, Madj, bufS1);

    // 2) z1 = s1 @ W1a + b1a + fused stats
    gemm_mfma<<<dim3(DD2 / BN, NTOT / BM), 256, 0, stream>>>(bufS1, Wt1a, b1a, zb, psum, psumsq, NTOT, DD2, DIN);
    bn_finalize<<<2, 256, 0, stream>>>(psum, psumsq, g1a, be1a, DD2, scale, shift);
    bn_apply_vec<<<(NTOT * DD2) / 2048, 256, 0, stream>>>(zb, scale, shift, bufC, DD2 - 1);

    // 4) h1 = z1n @ W1b + b1b + fused stats
    gemm_mfma<<<dim3(DD / BN, NTOT / BM), 256, 0, stream>>>(bufC, Wt1b, b1b, zb, psum, psumsq, NTOT, DD, DD2);
    bn_finalize<<<1, 256, 0, stream>>>(psum, psumsq, g1, be1, DD, scale, shift);

    // 5+6) s2 = bf16(M @ post), post = relu(BN(h1))+vemb fused in staging
    agg2_mm<<<dim3(2, BGR), 256, 0, stream>>>(zb, scale, shift, vemb, Madj, bufD);

    // 7) z2 = s2 @ W2a + b2a + fused stats
    gemm_mfma<<<dim3(DD2 / BN, NTOT / BM), 256, 0, stream>>>(bufD, Wt2a, b2a, zb, psum, psumsq, NTOT, DD2, DD);
    bn_finalize<<<2, 256, 0, stream>>>(psum, psumsq, g2a, be2a, DD2, scale, shift);
    bn_apply_vec<<<(NTOT * DD2) / 2048, 256, 0, stream>>>(zb, scale, shift, bufC, DD2 - 1);

    // 9) h2 = z2n @ W2b + b2b + fused stats
    gemm_mfma<<<dim3(DD / BN, NTOT / BM), 256, 0, stream>>>(bufC, Wt2b, b2b, zb, psum, psumsq, NTOT, DD, DD2);
    bn_finalize<<<1, 256, 0, stream>>>(psum, psumsq, g2, be2, DD, scale, shift);

    // 10) pa/pb with BN folded (grid-wide TLP)
    node_dots_bn<<<NTOT / 4, 256, 0, stream>>>(zb, scale, shift, Wl, pa, pb);

    // 11-12) per-graph scores + stable sort + gathers
    sort_write<<<BGR, EPG, 0, stream>>>(pa, pb, bl, ei, out);
}

// Round 7
// 311.579 us; speedup vs baseline: 2.7711x; 1.1063x over previous
//
#include <hip/hip_runtime.h>

// Problem constants
#define BGR   256
#define NPG   128
#define EPG   512
#define DIN   128
#define DD    256
#define DD2   512
#define NTOT  (BGR * NPG)   // 32768
#define ETOT  (BGR * EPG)   // 131072
#define NRES  (EPG / 2)
#define NCHUNK 256
#define MP    136           // padded LDS stride

// Output layout (floats)
#define OFF_CEI  0
#define OFF_CW   (2 * BGR * NRES)
#define OFF_FEI  (OFF_CW + BGR * NRES)
#define OFF_FW   (OFF_FEI + 2 * BGR * NRES)
#define OFF_PRED (OFF_FW + BGR * NRES)

typedef unsigned short ushortt;
typedef __attribute__((ext_vector_type(4))) unsigned short us4;
typedef __attribute__((ext_vector_type(8))) unsigned short us8;
typedef __attribute__((ext_vector_type(8))) short short8;
typedef __attribute__((ext_vector_type(4))) float f32x4;

__device__ __forceinline__ ushortt f2bf(float f) {
    unsigned int u = __float_as_uint(f);
    unsigned int r = (u + 0x7fffu + ((u >> 16) & 1u)) >> 16;
    return (ushortt)r;
}
__device__ __forceinline__ float bf2f(ushortt u) {
    return __uint_as_float(((unsigned int)u) << 16);
}

__device__ __forceinline__ void g2lds16(const void* g, void* l) {
    __builtin_amdgcn_global_load_lds(
        (const __attribute__((address_space(1))) unsigned int*)g,
        (__attribute__((address_space(3))) unsigned int*)l, 16, 0, 0);
}

// ---------------------------------------------------------------------------
// Prep: weight transposes (blocks 0..1791) + adjacency matrices (1792..2047).
__global__ __launch_bounds__(256) void prep(const float* __restrict__ W1a,
                                            const float* __restrict__ W1b,
                                            const float* __restrict__ W2a,
                                            const float* __restrict__ W2b,
                                            const int* __restrict__ ei,
                                            ushortt* __restrict__ Wt1a,
                                            ushortt* __restrict__ Wt1b,
                                            ushortt* __restrict__ Wt2a,
                                            ushortt* __restrict__ Wt2b,
                                            ushortt* __restrict__ Madj) {
    __shared__ int cnt[NPG * NPG];   // 64 KB (used by adj blocks only)
    const int t = threadIdx.x;
    if (blockIdx.x < 1792) {
        const int idx = blockIdx.x * 256 + t;
        if (idx < 65536) {                       // W1a: 128x512
            const int k = idx >> 9, n = idx & 511;
            Wt1a[n * DIN + k] = f2bf(W1a[idx]);
        } else if (idx < 196608) {               // W1b: 512x256
            const int i = idx - 65536;
            const int k = i >> 8, n = i & 255;
            Wt1b[n * DD2 + k] = f2bf(W1b[i]);
        } else if (idx < 327680) {               // W2a: 256x512
            const int i = idx - 196608;
            const int k = i >> 9, n = i & 511;
            Wt2a[n * DD + k] = f2bf(W2a[i]);
        } else if (idx < 458752) {               // W2b: 512x256
            const int i = idx - 327680;
            const int k = i >> 8, n = i & 255;
            Wt2b[n * DD2 + k] = f2bf(W2b[i]);
        }
        return;
    }
    const int b = blockIdx.x - 1792;
    for (int i = t; i < NPG * NPG; i += 256) cnt[i] = 0;
    __syncthreads();
    for (int e = t; e < EPG; e += 256) {
        const int src = ei[b * EPG + e] - b * NPG;
        const int dst = ei[ETOT + b * EPG + e] - b * NPG;
        atomicAdd(&cnt[dst * NPG + src], 1);
    }
    __syncthreads();
#pragma unroll
    for (int k = 0; k < 8; ++k) {
        const int i0 = (t + k * 256) * 8;
        us8 o;
#pragma unroll
        for (int e = 0; e < 8; ++e) {
            const int i = i0 + e;
            const int v = cnt[i] + (((i >> 7) == (i & 127)) ? 1 : 0);
            o[e] = f2bf((float)v);
        }
        *(us8*)&Madj[(size_t)b * NPG * NPG + i0] = o;
    }
}

// ---------------------------------------------------------------------------
// Layer-1 aggregate as MFMA: s1 = bf16( M @ bf16(x) ).  One block per graph.
__global__ __launch_bounds__(256) void agg1_mm(const float* __restrict__ x,
                                               const ushortt* __restrict__ Madj,
                                               ushortt* __restrict__ s1) {
    __shared__ ushortt Ms[NPG * MP];
    __shared__ ushortt XT[DIN * MP];
    const int b = blockIdx.x, t = threadIdx.x;
    const int wave = t >> 6, lane = t & 63;
    const int qd = lane >> 4, r = lane & 15;
    const ushortt* Mg = Madj + (size_t)b * NPG * NPG;
#pragma unroll
    for (int k = 0; k < 8; ++k) {
        const int ch = t + k * 256;
        const int m = ch >> 4, sc = (ch & 15) * 8;
        *(us8*)&Ms[m * MP + sc] = *(const us8*)&Mg[m * NPG + sc];
    }
#pragma unroll 4
    for (int it = 0; it < 64; ++it) {
        const int s = it * 2 + (t >> 7);
        const int c = t & 127;
        XT[c * MP + s] = f2bf(x[(size_t)(b * NPG + s) * DIN + c]);
    }
    __syncthreads();
    const int wm = (wave >> 1) * 64, wn = (wave & 1) * 64;
    f32x4 acc[4][4] = {};
#pragma unroll
    for (int ks = 0; ks < 4; ++ks) {
        const int k0 = ks * 32 + qd * 8;
        short8 af[4], bfr[4];
#pragma unroll
        for (int i = 0; i < 4; ++i)
            af[i] = *(const short8*)&Ms[(wm + i * 16 + r) * MP + k0];
#pragma unroll
        for (int j = 0; j < 4; ++j)
            bfr[j] = *(const short8*)&XT[(wn + j * 16 + r) * MP + k0];
#pragma unroll
        for (int i = 0; i < 4; ++i)
#pragma unroll
            for (int j = 0; j < 4; ++j)
                acc[i][j] = __builtin_amdgcn_mfma_f32_16x16x32_bf16(af[i], bfr[j], acc[i][j], 0, 0, 0);
    }
    __syncthreads();
    ushortt* Cs = Ms;
#pragma unroll
    for (int j = 0; j < 4; ++j) {
        const int coll = wn + j * 16 + r;
#pragma unroll
        for (int i = 0; i < 4; ++i)
#pragma unroll
            for (int tt = 0; tt < 4; ++tt)
                Cs[(wm + i * 16 + qd * 4 + tt) * DIN + coll] = f2bf(acc[i][j][tt]);
    }
    __syncthreads();
#pragma unroll
    for (int k = 0; k < 8; ++k) {
        const int ch = t + k * 256;
        const int row = ch >> 4, colc = (ch & 15) * 8;
        *(us8*)&s1[(size_t)(b * NPG + row) * DIN + colc] = *(const us8*)&Cs[row * DIN + colc];
    }
}

// ---------------------------------------------------------------------------
// Layer-2 aggregate as MFMA with FUSED bn_finalize (from psum/psumsq of the
// h1 GEMM) and BN+relu+vemb fused into the transpose staging.
__global__ __launch_bounds__(256) void agg2_mm(const ushortt* __restrict__ h,
                                               const float* __restrict__ psum,
                                               const float* __restrict__ psumsq,
                                               const float* __restrict__ g,
                                               const float* __restrict__ be,
                                               const float* __restrict__ vemb,
                                               const ushortt* __restrict__ Madj,
                                               ushortt* __restrict__ s2) {
    __shared__ ushortt Ms[NPG * MP];
    __shared__ ushortt PT[NPG * MP];
    __shared__ double redS[2][128];
    __shared__ double redQ[2][128];
    __shared__ float scs[128], shs[128];
    const int nb = blockIdx.x, b = blockIdx.y, t = threadIdx.x;
    const int wave = t >> 6, lane = t & 63;
    const int qd = lane >> 4, r = lane & 15;
    // stage M
    const ushortt* Mg = Madj + (size_t)b * NPG * NPG;
#pragma unroll
    for (int k = 0; k < 8; ++k) {
        const int ch = t + k * 256;
        const int m = ch >> 4, sc = (ch & 15) * 8;
        *(us8*)&Ms[m * MP + sc] = *(const us8*)&Mg[m * NPG + sc];
    }
    // fused finalize for this block's 128 columns
    {
        const int cl = t & 127, half = t >> 7;
        const int c = nb * 128 + cl;
        double s = 0.0, q = 0.0;
#pragma unroll 4
        for (int k = half * 128; k < half * 128 + 128; ++k) {
            s += (double)psum[(size_t)k * DD + c];
            q += (double)psumsq[(size_t)k * DD + c];
        }
        redS[half][cl] = s;
        redQ[half][cl] = q;
    }
    __syncthreads();
    if (t < 128) {
        const int c = nb * 128 + t;
        const double s = redS[0][t] + redS[1][t];
        const double q = redQ[0][t] + redQ[1][t];
        const double mean = s / (double)NTOT;
        const double var = q / (double)NTOT - mean * mean;
        const double rs = 1.0 / sqrt(var + 1e-5);
        const float sc = (float)((double)g[c] * rs);
        scs[t] = sc;
        shs[t] = (float)((double)be[c] - mean * (double)sc);
    }
    __syncthreads();
    // post staging with BN+relu+vemb
    const int cl = t & 127;
    const int c = nb * 128 + cl;
    const float scv = scs[cl], shv = shs[cl], vev = vemb[c];
#pragma unroll 4
    for (int it = 0; it < 64; ++it) {
        const int s = it * 2 + (t >> 7);
        float v = fmaf(bf2f(h[(size_t)(b * NPG + s) * DD + c]), scv, shv);
        PT[cl * MP + s] = f2bf(fmaxf(v, 0.0f) + vev);
    }
    __syncthreads();
    const int wm = (wave >> 1) * 64, wn = (wave & 1) * 64;
    f32x4 acc[4][4] = {};
#pragma unroll
    for (int ks = 0; ks < 4; ++ks) {
        const int k0 = ks * 32 + qd * 8;
        short8 af[4], bfr[4];
#pragma unroll
        for (int i = 0; i < 4; ++i)
            af[i] = *(const short8*)&Ms[(wm + i * 16 + r) * MP + k0];
#pragma unroll
        for (int j = 0; j < 4; ++j)
            bfr[j] = *(const short8*)&PT[(wn + j * 16 + r) * MP + k0];
#pragma unroll
        for (int i = 0; i < 4; ++i)
#pragma unroll
            for (int j = 0; j < 4; ++j)
                acc[i][j] = __builtin_amdgcn_mfma_f32_16x16x32_bf16(af[i], bfr[j], acc[i][j], 0, 0, 0);
    }
    __syncthreads();
    ushortt* Cs = Ms;
#pragma unroll
    for (int j = 0; j < 4; ++j) {
        const int coll = wn + j * 16 + r;
#pragma unroll
        for (int i = 0; i < 4; ++i)
#pragma unroll
            for (int tt = 0; tt < 4; ++tt)
                Cs[(wm + i * 16 + qd * 4 + tt) * 128 + coll] = f2bf(acc[i][j][tt]);
    }
    __syncthreads();
#pragma unroll
    for (int k = 0; k < 8; ++k) {
        const int ch = t + k * 256;
        const int row = ch >> 4, colc = (ch & 15) * 8;
        *(us8*)&s2[(size_t)(b * NPG + row) * DD + nb * 128 + colc] =
            *(const us8*)&Cs[row * 128 + colc];
    }
}

// ---------------------------------------------------------------------------
// bf16 MFMA GEMM (plain A): C = A@Wt^T + bias, fused fp32 BN partials,
// LDS-transposed coalesced C store.
#define BM 128
#define BN 128
#define BK 32
__global__ __launch_bounds__(256) void gemm_mfma(const ushortt* __restrict__ A,
                                                 const ushortt* __restrict__ Wt,
                                                 const float* __restrict__ bias,
                                                 ushortt* __restrict__ C,
                                                 float* __restrict__ psum,
                                                 float* __restrict__ psumsq,
                                                 int M, int N, int K) {
    __shared__ ushortt As[BM * BK];
    __shared__ ushortt Bs[BN * BK];
    __shared__ ushortt Cs[BM * BN];
    __shared__ float redS[2][BN];
    __shared__ float redQ[2][BN];
    const int tid  = threadIdx.x;
    const int wave = tid >> 6;
    const int lane = tid & 63;
    const int qd = lane >> 4;
    const int r  = lane & 15;
    const int wm = (wave >> 1) * 64;
    const int wn = (wave & 1) * 64;
    const int m0 = blockIdx.y * BM;
    const int n0 = blockIdx.x * BN;

    f32x4 acc[4][4] = {};

    for (int k0 = 0; k0 < K; k0 += BK) {
#pragma unroll
        for (int s = 0; s < 2; ++s) {
            const int o   = wave * 128 + s * 64 + lane;
            const int row = o >> 2;
            const int cg  = o & 3;
            g2lds16(A  + (size_t)(m0 + row) * K + k0 + cg * 8,
                    &As[(size_t)(wave * 128 + s * 64) * 8]);
            g2lds16(Wt + (size_t)(n0 + row) * K + k0 + cg * 8,
                    &Bs[(size_t)(wave * 128 + s * 64) * 8]);
        }
        __syncthreads();
        short8 af[4], bfr[4];
#pragma unroll
        for (int i = 0; i < 4; ++i)
            af[i] = *(const short8*)&As[(wm + i * 16 + r) * BK + qd * 8];
#pragma unroll
        for (int j = 0; j < 4; ++j)
            bfr[j] = *(const short8*)&Bs[(wn + j * 16 + r) * BK + qd * 8];
#pragma unroll
        for (int i = 0; i < 4; ++i)
#pragma unroll
            for (int j = 0; j < 4; ++j)
                acc[i][j] = __builtin_amdgcn_mfma_f32_16x16x32_bf16(af[i], bfr[j], acc[i][j], 0, 0, 0);
        __syncthreads();
    }

#pragma unroll
    for (int j = 0; j < 4; ++j) {
        const int coll = wn + j * 16 + r;
        const float bv = bias[n0 + coll];
        float s = 0.0f, q = 0.0f;
#pragma unroll
        for (int i = 0; i < 4; ++i) {
#pragma unroll
            for (int t = 0; t < 4; ++t) {
                const float v = acc[i][j][t] + bv;
                Cs[(wm + i * 16 + qd * 4 + t) * BN + coll] = f2bf(v);
                s += v;
                q = fmaf(v, v, q);
            }
        }
        s += __shfl_xor(s, 16); s += __shfl_xor(s, 32);
        q += __shfl_xor(q, 16); q += __shfl_xor(q, 32);
        if (qd == 0) {
            redS[wave >> 1][coll] = s;
            redQ[wave >> 1][coll] = q;
        }
    }
    __syncthreads();
    if (tid < BN) {
        psum[(size_t)blockIdx.y * N + n0 + tid]   = redS[0][tid] + redS[1][tid];
        psumsq[(size_t)blockIdx.y * N + n0 + tid] = redQ[0][tid] + redQ[1][tid];
    }
#pragma unroll
    for (int s8 = 0; s8 < 8; ++s8) {
        const int c    = tid + 256 * s8;
        const int row  = c >> 4;
        const int colc = (c & 15) * 8;
        const us8 v = *(const us8*)&Cs[row * BN + colc];
        *(us8*)&C[(size_t)(m0 + row) * N + n0 + colc] = v;
    }
}

// ---------------------------------------------------------------------------
// bf16 MFMA GEMM with BN-apply+ReLU FUSED into A staging:
// A' = bf16(relu(A*scale[k]+shift[k])); C = A'@Wt^T + bias; stats fused.
// B stays on the async global_load_lds path; A goes regs->ds_write_b128.
__global__ __launch_bounds__(256) void gemm_mfma_bn(const ushortt* __restrict__ A,
                                                    const ushortt* __restrict__ Wt,
                                                    const float* __restrict__ scale,
                                                    const float* __restrict__ shift,
                                                    const float* __restrict__ bias,
                                                    ushortt* __restrict__ C,
                                                    float* __restrict__ psum,
                                                    float* __restrict__ psumsq,
                                                    int M, int N, int K) {
    __shared__ ushortt As[BM * BK];
    __shared__ ushortt Bs[BN * BK];
    __shared__ ushortt Cs[BM * BN];
    __shared__ float redS[2][BN];
    __shared__ float redQ[2][BN];
    __shared__ float scs[DD2], shs[DD2];
    const int tid  = threadIdx.x;
    const int wave = tid >> 6;
    const int lane = tid & 63;
    const int qd = lane >> 4;
    const int r  = lane & 15;
    const int wm = (wave >> 1) * 64;
    const int wn = (wave & 1) * 64;
    const int m0 = blockIdx.y * BM;
    const int n0 = blockIdx.x * BN;

    for (int i = tid; i < K; i += 256) {
        scs[i] = scale[i];
        shs[i] = shift[i];
    }
    __syncthreads();

    f32x4 acc[4][4] = {};

    for (int k0 = 0; k0 < K; k0 += BK) {
#pragma unroll
        for (int s = 0; s < 2; ++s) {
            const int o   = wave * 128 + s * 64 + lane;
            const int row = o >> 2;
            const int cg  = o & 3;
            g2lds16(Wt + (size_t)(n0 + row) * K + k0 + cg * 8,
                    &Bs[(size_t)(wave * 128 + s * 64) * 8]);
        }
#pragma unroll
        for (int s = 0; s < 2; ++s) {
            const int o   = wave * 128 + s * 64 + lane;
            const int row = o >> 2;
            const int cg  = o & 3;
            const us8 a8 = *(const us8*)&A[(size_t)(m0 + row) * K + k0 + cg * 8];
            const float4 s4a = *(const float4*)&scs[k0 + cg * 8];
            const float4 s4b = *(const float4*)&scs[k0 + cg * 8 + 4];
            const float4 h4a = *(const float4*)&shs[k0 + cg * 8];
            const float4 h4b = *(const float4*)&shs[k0 + cg * 8 + 4];
            us8 t8;
            t8[0] = f2bf(fmaxf(fmaf(bf2f(a8[0]), s4a.x, h4a.x), 0.0f));
            t8[1] = f2bf(fmaxf(fmaf(bf2f(a8[1]), s4a.y, h4a.y), 0.0f));
            t8[2] = f2bf(fmaxf(fmaf(bf2f(a8[2]), s4a.z, h4a.z), 0.0f));
            t8[3] = f2bf(fmaxf(fmaf(bf2f(a8[3]), s4a.w, h4a.w), 0.0f));
            t8[4] = f2bf(fmaxf(fmaf(bf2f(a8[4]), s4b.x, h4b.x), 0.0f));
            t8[5] = f2bf(fmaxf(fmaf(bf2f(a8[5]), s4b.y, h4b.y), 0.0f));
            t8[6] = f2bf(fmaxf(fmaf(bf2f(a8[6]), s4b.z, h4b.z), 0.0f));
            t8[7] = f2bf(fmaxf(fmaf(bf2f(a8[7]), s4b.w, h4b.w), 0.0f));
            *(us8*)&As[row * BK + cg * 8] = t8;
        }
        __syncthreads();
        short8 af[4], bfr[4];
#pragma unroll
        for (int i = 0; i < 4; ++i)
            af[i] = *(const short8*)&As[(wm + i * 16 + r) * BK + qd * 8];
#pragma unroll
        for (int j = 0; j < 4; ++j)
            bfr[j] = *(const short8*)&Bs[(wn + j * 16 + r) * BK + qd * 8];
#pragma unroll
        for (int i = 0; i < 4; ++i)
#pragma unroll
            for (int j = 0; j < 4; ++j)
                acc[i][j] = __builtin_amdgcn_mfma_f32_16x16x32_bf16(af[i], bfr[j], acc[i][j], 0, 0, 0);
        __syncthreads();
    }

#pragma unroll
    for (int j = 0; j < 4; ++j) {
        const int coll = wn + j * 16 + r;
        const float bv = bias[n0 + coll];
        float s = 0.0f, q = 0.0f;
#pragma unroll
        for (int i = 0; i < 4; ++i) {
#pragma unroll
            for (int t = 0; t < 4; ++t) {
                const float v = acc[i][j][t] + bv;
                Cs[(wm + i * 16 + qd * 4 + t) * BN + coll] = f2bf(v);
                s += v;
                q = fmaf(v, v, q);
            }
        }
        s += __shfl_xor(s, 16); s += __shfl_xor(s, 32);
        q += __shfl_xor(q, 16); q += __shfl_xor(q, 32);
        if (qd == 0) {
            redS[wave >> 1][coll] = s;
            redQ[wave >> 1][coll] = q;
        }
    }
    __syncthreads();
    if (tid < BN) {
        psum[(size_t)blockIdx.y * N + n0 + tid]   = redS[0][tid] + redS[1][tid];
        psumsq[(size_t)blockIdx.y * N + n0 + tid] = redQ[0][tid] + redQ[1][tid];
    }
#pragma unroll
    for (int s8 = 0; s8 < 8; ++s8) {
        const int c    = tid + 256 * s8;
        const int row  = c >> 4;
        const int colc = (c & 15) * 8;
        const us8 v = *(const us8*)&Cs[row * BN + colc];
        *(us8*)&C[(size_t)(m0 + row) * N + n0 + colc] = v;
    }
}

// ---------------------------------------------------------------------------
__global__ __launch_bounds__(256) void bn_finalize(const float* __restrict__ psum,
                                                   const float* __restrict__ psumsq,
                                                   const float* __restrict__ g,
                                                   const float* __restrict__ be,
                                                   int ncols,
                                                   float* __restrict__ scale,
                                                   float* __restrict__ shift) {
    const int c = blockIdx.x * 256 + threadIdx.x;
    double s = 0.0, s2 = 0.0;
    for (int k = 0; k < NCHUNK; ++k) {
        s += (double)psum[(size_t)k * ncols + c];
        s2 += (double)psumsq[(size_t)k * ncols + c];
    }
    const double mean = s / (double)NTOT;
    const double var = s2 / (double)NTOT - mean * mean;
    const double rs = 1.0 / sqrt(var + 1e-5);
    const float sc = (float)((double)g[c] * rs);
    scale[c] = sc;
    shift[c] = (float)((double)be[c] - mean * (double)sc);
}

// ---------------------------------------------------------------------------
// Mega tail: per-graph block (512 thr). Fused finalize(g2,be2) -> node dots
// (BN folded) -> edge scores -> stable descending rank-sort -> output writes.
__global__ __launch_bounds__(EPG) void sort_mega(const ushortt* __restrict__ h2,
                                                 const float* __restrict__ psum,
                                                 const float* __restrict__ psumsq,
                                                 const float* __restrict__ g,
                                                 const float* __restrict__ be,
                                                 const float* __restrict__ Wl,
                                                 const float* __restrict__ bl,
                                                 const int* __restrict__ ei,
                                                 float* __restrict__ out) {
    __shared__ double redS[2][DD];
    __shared__ double redQ[2][DD];
    __shared__ float scs[DD], shs[DD];
    __shared__ float pa[NPG], pb[NPG];
    __shared__ float pw[EPG];
    __shared__ int ord[EPG];
    const int b = blockIdx.x, t = threadIdx.x;
    // Phase A: finalize (512 threads: 2 half-chunks x 256 cols)
    {
        const int c = t & 255, half = t >> 8;
        double s = 0.0, q = 0.0;
#pragma unroll 4
        for (int k = half * 128; k < half * 128 + 128; ++k) {
            s += (double)psum[(size_t)k * DD + c];
            q += (double)psumsq[(size_t)k * DD + c];
        }
        redS[half][c] = s;
        redQ[half][c] = q;
    }
    __syncthreads();
    if (t < DD) {
        const double s = redS[0][t] + redS[1][t];
        const double q = redQ[0][t] + redQ[1][t];
        const double mean = s / (double)NTOT;
        const double var = q / (double)NTOT - mean * mean;
        const double rs = 1.0 / sqrt(var + 1e-5);
        const float sc = (float)((double)g[t] * rs);
        scs[t] = sc;
        shs[t] = (float)((double)be[t] - mean * (double)sc);
    }
    __syncthreads();
    // Phase B: node dots (8 waves, 16 nodes each)
    {
        const int wave = t >> 6, lane = t & 63;
        const float4 w0 = *(const float4*)&Wl[lane * 4];
        const float4 w1 = *(const float4*)&Wl[DD + lane * 4];
        const float4 sc4 = *(const float4*)&scs[lane * 4];
        const float4 sh4 = *(const float4*)&shs[lane * 4];
        for (int n = wave; n < NPG; n += 8) {
            const us4 z4 = *(const us4*)&h2[(size_t)(b * NPG + n) * DD + lane * 4];
            const float x0 = fmaf(bf2f(z4.x), sc4.x, sh4.x);
            const float x1 = fmaf(bf2f(z4.y), sc4.y, sh4.y);
            const float x2 = fmaf(bf2f(z4.z), sc4.z, sh4.z);
            const float x3 = fmaf(bf2f(z4.w), sc4.w, sh4.w);
            float sa = x0 * w0.x + x1 * w0.y + x2 * w0.z + x3 * w0.w;
            float sb = x0 * w1.x + x1 * w1.y + x2 * w1.z + x3 * w1.w;
#pragma unroll
            for (int off = 32; off >= 1; off >>= 1) {
                sa += __shfl_down(sa, off);
                sb += __shfl_down(sb, off);
            }
            if (lane == 0) { pa[n] = sa; pb[n] = sb; }
        }
    }
    __syncthreads();
    // Phase C: scores + stable sort + writes (t == edge index)
    const int rl = ei[b * EPG + t] - b * NPG;
    const int cl = ei[ETOT + b * EPG + t] - b * NPG;
    const float v = pa[rl] + pb[cl] + bl[0];
    pw[t] = v;
    out[OFF_PRED + b * EPG + t] = v;
    __syncthreads();
    int rank = 0;
#pragma unroll 8
    for (int k = 0; k < EPG; ++k) {
        const float u = pw[k];
        rank += (u > v) || (u == v && k < t);
    }
    ord[rank] = t;
    __syncthreads();
    const int j = ord[t];
    const float wv = pw[j];
    const float e0 = (float)ei[b * EPG + j];
    const float e1 = (float)ei[ETOT + b * EPG + j];
    if (t < NRES) {
        out[OFF_CEI + b * NRES + t] = e0;
        out[OFF_CEI + BGR * NRES + b * NRES + t] = e1;
        out[OFF_CW + b * NRES + t] = wv;
    } else {
        const int p = t - NRES;
        out[OFF_FEI + b * NRES + p] = e0;
        out[OFF_FEI + BGR * NRES + b * NRES + p] = e1;
        out[OFF_FW + b * NRES + p] = -wv;
    }
}

// ---------------------------------------------------------------------------
extern "C" void kernel_launch(void* const* d_in, const int* in_sizes, int n_in,
                              void* d_out, int out_size, void* d_ws, size_t ws_size,
                              hipStream_t stream) {
    (void)in_sizes; (void)n_in; (void)out_size; (void)ws_size;
    const float* x    = (const float*)d_in[0];
    const int*   ei   = (const int*)d_in[1];
    const float* vemb = (const float*)d_in[3];
    const float* W1a  = (const float*)d_in[4];
    const float* b1a  = (const float*)d_in[5];
    const float* g1a  = (const float*)d_in[6];
    const float* be1a = (const float*)d_in[7];
    const float* W1b  = (const float*)d_in[8];
    const float* b1b  = (const float*)d_in[9];
    const float* g1   = (const float*)d_in[10];
    const float* be1  = (const float*)d_in[11];
    const float* W2a  = (const float*)d_in[12];
    const float* b2a  = (const float*)d_in[13];
    const float* g2a  = (const float*)d_in[14];
    const float* be2a = (const float*)d_in[15];
    const float* W2b  = (const float*)d_in[16];
    const float* b2b  = (const float*)d_in[17];
    const float* g2   = (const float*)d_in[18];
    const float* be2  = (const float*)d_in[19];
    const float* Wl   = (const float*)d_in[20];
    const float* bl   = (const float*)d_in[21];
    float* out = (float*)d_out;

    char* wp = (char*)d_ws;
    auto alloc = [&](size_t bytes) -> char* {
        char* r = wp;
        wp += (bytes + 255) & ~(size_t)255;
        return r;
    };
    ushortt* zb    = (ushortt*)alloc((size_t)NTOT * 512 * 2);  // z1 / z2
    ushortt* bufC  = (ushortt*)alloc((size_t)NTOT * 256 * 2);  // h1 / h2
    ushortt* bufD  = (ushortt*)alloc((size_t)NTOT * 256 * 2);  // s2
    ushortt* bufS1 = (ushortt*)alloc((size_t)NTOT * 128 * 2);  // s1
    ushortt* Madj  = (ushortt*)alloc((size_t)BGR * NPG * NPG * 2);
    ushortt* Wt1a  = (ushortt*)alloc((size_t)DIN * DD2 * 2);
    ushortt* Wt1b  = (ushortt*)alloc((size_t)DD2 * DD * 2);
    ushortt* Wt2a  = (ushortt*)alloc((size_t)DD * DD2 * 2);
    ushortt* Wt2b  = (ushortt*)alloc((size_t)DD2 * DD * 2);
    float*   psum   = (float*)alloc((size_t)NCHUNK * 512 * 4);
    float*   psumsq = (float*)alloc((size_t)NCHUNK * 512 * 4);
    float*   scale  = (float*)alloc(512 * 4);
    float*   shift  = (float*)alloc(512 * 4);

    // 0) weights + adjacency
    prep<<<2048, 256, 0, stream>>>(W1a, W1b, W2a, W2b, ei,
                                   Wt1a, Wt1b, Wt2a, Wt2b, Madj);

    // 1) s1 = bf16(M @ bf16(x))
    agg1_mm<<<BGR, 256, 0, stream>>>(x, Madj, bufS1);

    // 2) z1 = s1 @ W1a + b1a  (+stats)
    gemm_mfma<<<dim3(DD2 / BN, NTOT / BM), 256, 0, stream>>>(bufS1, Wt1a, b1a, zb, psum, psumsq, NTOT, DD2, DIN);
    bn_finalize<<<2, 256, 0, stream>>>(psum, psumsq, g1a, be1a, DD2, scale, shift);

    // 3) h1 = relu(BN(z1)) @ W1b + b1b  (BN-apply fused into A staging, +stats)
    gemm_mfma_bn<<<dim3(DD / BN, NTOT / BM), 256, 0, stream>>>(zb, Wt1b, scale, shift, b1b, bufC, psum, psumsq, NTOT, DD, DD2);

    // 4) s2 = bf16(M @ post), finalize(g1)+BN+relu+vemb fused
    agg2_mm<<<dim3(2, BGR), 256, 0, stream>>>(bufC, psum, psumsq, g1, be1, vemb, Madj, bufD);

    // 5) z2 = s2 @ W2a + b2a  (+stats)
    gemm_mfma<<<dim3(DD2 / BN, NTOT / BM), 256, 0, stream>>>(bufD, Wt2a, b2a, zb, psum, psumsq, NTOT, DD2, DD);
    bn_finalize<<<2, 256, 0, stream>>>(psum, psumsq, g2a, be2a, DD2, scale, shift);

    // 6) h2 = relu(BN(z2)) @ W2b + b2b  (fused, +stats)
    gemm_mfma_bn<<<dim3(DD / BN, NTOT / BM), 256, 0, stream>>>(zb, Wt2b, scale, shift, b2b, bufC, psum, psumsq, NTOT, DD, DD2);

    // 7) mega tail: finalize(g2) + dots + scores + stable sort + writes
    sort_mega<<<BGR, EPG, 0, stream>>>(bufC, psum, psumsq, g2, be2, Wl, bl, ei, out);
}